// Round 1
// baseline (904.551 us; speedup 1.0000x reference)
//
#include <hip/hip_runtime.h>
#include <math.h>

typedef unsigned short u16;
typedef float f32x4 __attribute__((ext_vector_type(4)));
typedef short bf16x8 __attribute__((ext_vector_type(8)));

#define NVIEW 6

// ---------- helpers ----------
__device__ __forceinline__ u16 f2bf(float f){
  unsigned u = __float_as_uint(f);
  u += 0x7FFFu + ((u >> 16) & 1u);      // round-to-nearest-even
  return (u16)(u >> 16);
}
__device__ __forceinline__ float bf2f(u16 h){
  return __uint_as_float(((unsigned)h) << 16);
}
__device__ __forceinline__ float fsig(float x){
  x = fminf(fmaxf(x, -30.f), 30.f);
  return 1.0f / (1.0f + __expf(-x));
}
__device__ __forceinline__ float ftanh(float x){
  x = fminf(fmaxf(x, -15.f), 15.f);
  float e = __expf(2.0f * x);
  return (e - 1.0f) / (e + 1.0f);
}
__device__ __forceinline__ void gload16(const u16* g, u16* l){
  __builtin_amdgcn_global_load_lds((const __attribute__((address_space(1))) unsigned int*)g,
                                   (__attribute__((address_space(3))) unsigned int*)l,
                                   16, 0, 0);
}

// ---------- setup kernels ----------
__global__ void k_cvt(const float* __restrict__ in, u16* __restrict__ out, long n4){
  long i = (long)blockIdx.x * blockDim.x + threadIdx.x;
  long stride = (long)gridDim.x * blockDim.x;
  for (; i < n4; i += stride){
    const float4 v = ((const float4*)in)[i];
    ushort4 o;
    o.x = f2bf(v.x); o.y = f2bf(v.y); o.z = f2bf(v.z); o.w = f2bf(v.w);
    ((ushort4*)out)[i] = o;
  }
}

// Wl[l][4u+q][k] = (k<256 ? Wih[l][q*256+u][k] : Whh[l][q*256+u][k-256]) as bf16
__global__ void k_build_wl(const float* __restrict__ Wih, const float* __restrict__ Whh,
                           u16* __restrict__ Wl){
  int idx = blockIdx.x * 256 + threadIdx.x;   // exactly 3*1024*512 threads
  int l   = idx >> 19;
  int rem = idx & 524287;
  int ro  = rem >> 9;       // interleaved out-row 0..1023
  int k   = rem & 511;
  int u = ro >> 2, q = ro & 3;
  int ri = q * 256 + u;
  float v = (k < 256) ? Wih[(l * 1024 + ri) * 256 + k]
                      : Whh[(l * 1024 + ri) * 256 + (k - 256)];
  Wl[idx] = f2bf(v);
}

__global__ void k_build_bias(const float* __restrict__ bih, const float* __restrict__ bhh,
                             float* __restrict__ biasL, u16* __restrict__ zbuf){
  int idx = blockIdx.x * 256 + threadIdx.x;
  if (idx < 3072){
    int l = idx >> 10; int ro = idx & 1023;
    int u = ro >> 2, q = ro & 3;
    int ri = q * 256 + u;
    biasL[idx] = bih[l * 1024 + ri] + bhh[l * 1024 + ri];
  }
  if (idx < 256) zbuf[idx] = 0;
}

// ---------- GEMM: C[m,n] = sum_k A[m,k]*B[n,k]  (B given as [N][K], bf16) ----------
// A is split in K: cols [0,K0) from A0 (row stride sA0), cols [K0,K) from A1 (stride sA1).
// EPI 0: out = bf16( gelu(acc + bias[n]) + resid[m*N+n] )          (fc_conv + GELU + residual)
// EPI 1: out = bf16( acc + bias[n] )                                (fc_in)
// EPI 2: fused LSTM cell. N=1024 gate-interleaved; unit u=n>>2, gate q=n&3.
//        reads/writes cbuf[row*256+u] (f32), writes h -> outb[(row*6+t)*256+u] (bf16).
template<int EPI>
__global__ __launch_bounds__(256)
void gemm_bt(const u16* __restrict__ A0, long sA0,
             const u16* __restrict__ A1, long sA1, int K0,
             const u16* __restrict__ Bm,
             int N, int K,
             const float* __restrict__ bias,
             const float* __restrict__ resid,
             u16* __restrict__ outb,
             float* __restrict__ cbuf,
             int tstep)
{
  __shared__ __align__(16) u16 lA[128 * 64];
  __shared__ __align__(16) u16 lB[128 * 64];

  const int tid  = threadIdx.x;
  const int lane = tid & 63;
  const int wid  = tid >> 6;
  const int wm = wid >> 1, wn = wid & 1;
  const int l15 = lane & 15, lk = lane >> 4;
  const long m0 = (long)blockIdx.x * 128;
  const int  n0 = blockIdx.y * 128;

  f32x4 acc[4][4];
  #pragma unroll
  for (int i = 0; i < 4; ++i)
    #pragma unroll
    for (int j = 0; j < 4; ++j)
      acc[i][j] = (f32x4){0.f, 0.f, 0.f, 0.f};

  const int rowL = tid >> 3;        // 0..31 per stage-call
  const int col8 = (tid & 7) * 8;   // element column within BK=64

  for (int kt = 0; kt < (K >> 6); ++kt){
    const int kbase = kt << 6;
    #pragma unroll
    for (int c = 0; c < 4; ++c){
      int r = c * 32 + rowL;
      int k = kbase + col8;
      const u16* src = (k < K0) ? (A0 + (m0 + r) * sA0 + k)
                                : (A1 + (m0 + r) * sA1 + (k - K0));
      gload16(src, &lA[r * 64 + col8]);
    }
    #pragma unroll
    for (int c = 0; c < 4; ++c){
      int r = c * 32 + rowL;
      int k = kbase + col8;
      gload16(Bm + (long)(n0 + r) * K + k, &lB[r * 64 + col8]);
    }
    __syncthreads();   // drains vmcnt before barrier (compiler-emitted)

    #pragma unroll
    for (int ks = 0; ks < 2; ++ks){
      bf16x8 af[4], bfr[4];
      #pragma unroll
      for (int mf = 0; mf < 4; ++mf)
        af[mf] = *(const bf16x8*)&lA[(wm * 64 + mf * 16 + l15) * 64 + ks * 32 + lk * 8];
      #pragma unroll
      for (int nf = 0; nf < 4; ++nf)
        bfr[nf] = *(const bf16x8*)&lB[(wn * 64 + nf * 16 + l15) * 64 + ks * 32 + lk * 8];
      #pragma unroll
      for (int mf = 0; mf < 4; ++mf)
        #pragma unroll
        for (int nf = 0; nf < 4; ++nf)
          acc[mf][nf] = __builtin_amdgcn_mfma_f32_16x16x32_bf16(af[mf], bfr[nf], acc[mf][nf], 0, 0, 0);
    }
    __syncthreads();
  }

  if (EPI == 0 || EPI == 1){
    #pragma unroll
    for (int mf = 0; mf < 4; ++mf){
      #pragma unroll
      for (int nf = 0; nf < 4; ++nf){
        int  n    = n0 + wn * 64 + nf * 16 + l15;
        long mrow = m0 + wm * 64 + mf * 16 + lk * 4;
        float bz = bias[n];
        #pragma unroll
        for (int r = 0; r < 4; ++r){
          float v = acc[mf][nf][r] + bz;
          long off = (mrow + r) * N + n;
          if (EPI == 0){
            float ge = 0.5f * v * (1.0f + erff(v * 0.70710678118654752f));
            v = ge + resid[off];
          }
          outb[off] = f2bf(v);
        }
      }
    }
  } else {
    // LSTM cell epilogue. D-frag: row=(lane>>4)*4+reg, col=lane&15 (m89-verified).
    // Quad lanes (lane&3 = q) hold gates i,f,g,o of unit u = n>>2 for the SAME 4 rows.
    // 4x4 quad transpose: lane a ends with all 4 gates of row (base + lk*4 + a).
    const int a  = lane & 3;
    const int qb = lane & ~3;
    #pragma unroll
    for (int mf = 0; mf < 4; ++mf){
      #pragma unroll
      for (int nf = 0; nf < 4; ++nf){
        int n = n0 + wn * 64 + nf * 16 + l15;
        float bz = bias[n];
        float v0 = acc[mf][nf][0] + bz;
        float v1 = acc[mf][nf][1] + bz;
        float v2 = acc[mf][nf][2] + bz;
        float v3 = acc[mf][nf][3] + bz;
        // s_d = t[(a+d)&3]
        float s0 = (a == 0) ? v0 : (a == 1) ? v1 : (a == 2) ? v2 : v3;
        float s1 = (a == 0) ? v1 : (a == 1) ? v2 : (a == 2) ? v3 : v0;
        float s2 = (a == 0) ? v2 : (a == 1) ? v3 : (a == 2) ? v0 : v1;
        float s3 = (a == 0) ? v3 : (a == 1) ? v0 : (a == 2) ? v1 : v2;
        // r_d = lane((a-d)&3)'s t[a]
        float r0 = s0;
        float r1 = __shfl(s1, qb + ((a + 3) & 3));
        float r2 = __shfl(s2, qb + ((a + 2) & 3));
        float r3 = __shfl(s3, qb + ((a + 1) & 3));
        // w[q] = r_{(a-q)&3}
        float wi = (a == 0) ? r0 : (a == 1) ? r1 : (a == 2) ? r2 : r3;
        float wf = (a == 1) ? r0 : (a == 2) ? r1 : (a == 3) ? r2 : r3;
        float wg = (a == 2) ? r0 : (a == 3) ? r1 : (a == 0) ? r2 : r3;
        float wo = (a == 3) ? r0 : (a == 0) ? r1 : (a == 1) ? r2 : r3;
        long row = m0 + wm * 64 + mf * 16 + lk * 4 + a;   // LSTM batch row (M=8192)
        int  u   = ((n0 + wn * 64 + nf * 16) >> 2) + (l15 >> 2);
        float c_old = (tstep == 0) ? 0.0f : cbuf[row * 256 + u];
        float ii = fsig(wi), ff = fsig(wf), gg = ftanh(wg), oo = fsig(wo);
        float cn = ff * c_old + ii * gg;
        float hn = oo * ftanh(cn);
        cbuf[row * 256 + u] = cn;
        outb[(row * NVIEW + tstep) * 256 + u] = f2bf(hn);
      }
    }
  }
}

// ---------- tail: viewport + score + mean ----------
__global__ void k_score(const u16* __restrict__ X3, const float* __restrict__ Wv,
                        const float* __restrict__ bv, const float* __restrict__ Ws,
                        const float* __restrict__ bs, float* __restrict__ score){
  int lane = threadIdx.x & 63;
  int bm = blockIdx.x * 4 + (threadIdx.x >> 6);
  const u16* row = X3 + (long)bm * (NVIEW * 256);
  float4 wv = *(const float4*)(Wv + lane * 4);
  float p = 0.f;
  #pragma unroll
  for (int n = 0; n < NVIEW; ++n){
    ushort4 xv = *(const ushort4*)(row + n * 256 + lane * 4);
    float d = bf2f(xv.x) * wv.x + bf2f(xv.y) * wv.y + bf2f(xv.z) * wv.z + bf2f(xv.w) * wv.w;
    p += Ws[n] * d;
  }
  #pragma unroll
  for (int off = 32; off; off >>= 1) p += __shfl_xor(p, off);
  if (lane == 0){
    float sw = Ws[0] + Ws[1] + Ws[2] + Ws[3] + Ws[4] + Ws[5];
    score[bm] = p + bv[0] * sw + bs[0];
  }
}

__global__ void k_mean(const float* __restrict__ score, float* __restrict__ out){
  __shared__ float red[256];
  int b = blockIdx.x, tid = threadIdx.x;
  red[tid] = score[b * 256 + tid];
  __syncthreads();
  for (int s = 128; s > 0; s >>= 1){
    if (tid < s) red[tid] += red[tid + s];
    __syncthreads();
  }
  if (tid == 0) out[b] = red[0] * (1.0f / 256.0f);
}

// ---------- launcher ----------
extern "C" void kernel_launch(void* const* d_in, const int* in_sizes, int n_in,
                              void* d_out, int out_size, void* d_ws, size_t ws_size,
                              hipStream_t stream){
  const float* swin = (const float*)d_in[0];
  const float* conv = (const float*)d_in[1];
  const float* Wc   = (const float*)d_in[2];
  const float* bc   = (const float*)d_in[3];
  const float* Win  = (const float*)d_in[4];
  const float* b_in = (const float*)d_in[5];
  const float* Wih  = (const float*)d_in[6];
  const float* Whh  = (const float*)d_in[7];
  const float* bih  = (const float*)d_in[8];
  const float* bhh  = (const float*)d_in[9];
  const float* Wv   = (const float*)d_in[10];
  const float* bv   = (const float*)d_in[11];
  const float* Ws   = (const float*)d_in[12];
  const float* bs   = (const float*)d_in[13];
  float* out = (float*)d_out;

  // workspace layout (~198 MB total)
  char* w = (char*)d_ws;
  u16*  convb = (u16*)(w);                    // 100,663,296 B  [49152*1024] bf16
  u16*  X0    = (u16*)(w);                    // reuses convb region after G1 (25,165,824)
  u16*  XA    = (u16*)(w + 25165824);         // 25,165,824
  u16*  XB    = (u16*)(w + 50331648);         // 25,165,824
  float* cbuf = (float*)(w + 75497472);       //  8,388,608
  u16*  Y     = (u16*)(w + 100663296);        // 100,663,296
  u16*  Wcb   = (u16*)(w + 201326592);        //  2,097,152
  u16*  Winb  = (u16*)(w + 203423744);        //    524,288
  u16*  Wl    = (u16*)(w + 203948032);        //  3,145,728
  float* biasL= (float*)(w + 207093760);      //     12,288
  u16*  zbuf  = (u16*)(w + 207106048);        //        512
  float* scoreb = (float*)(w + 207106560);    //     32,768

  // 1) converts + weight transforms
  k_cvt<<<4096, 256, 0, stream>>>(conv, convb, 49152L * 1024 / 4);
  k_cvt<<<512, 256, 0, stream>>>(Wc, Wcb, 1048576 / 4);
  k_cvt<<<128, 256, 0, stream>>>(Win, Winb, 262144 / 4);
  k_build_wl<<<6144, 256, 0, stream>>>(Wih, Whh, Wl);
  k_build_bias<<<12, 256, 0, stream>>>(bih, bhh, biasL, zbuf);

  // 2) G1: Y = bf16( gelu(conv @ Wc^T + bc) + swin )   [49152 x 1024]
  gemm_bt<0><<<dim3(384, 8), 256, 0, stream>>>(
      convb, 1024L, convb, 1024L, 1024,
      Wcb, 1024, 1024, bc, swin, Y, (float*)nullptr, 0);

  // 3) G2: X0 = bf16( Y @ Win^T + b_in )               [49152 x 256]
  gemm_bt<1><<<dim3(384, 2), 256, 0, stream>>>(
      Y, 1024L, Y, 1024L, 1024,
      Winb, 256, 1024, b_in, (const float*)nullptr, X0, (float*)nullptr, 0);

  // 4) LSTM: 3 layers x 6 timesteps; gates = [x_t, h_{t-1}] @ Wl^T + bias (K=512)
  const u16* xin = X0;
  u16* xout = XA;
  for (int l = 0; l < 3; ++l){
    for (int t = 0; t < 6; ++t){
      const u16* a1 = (t == 0) ? zbuf : (xout + (t - 1) * 256);
      long s1 = (t == 0) ? 0L : 1536L;
      gemm_bt<2><<<dim3(64, 8), 256, 0, stream>>>(
          xin + t * 256, 1536L, a1, s1, 256,
          Wl + l * 1024 * 512, 1024, 512,
          biasL + l * 1024, (const float*)nullptr,
          xout, cbuf, t);
    }
    if (l == 0){ xin = XA; xout = XB; }
    else if (l == 1){ xin = XB; xout = XA; }
  }
  // X3 = XA

  // 5) viewport + score + mean
  k_score<<<2048, 256, 0, stream>>>(XA, Wv, bv, Ws, bs, scoreb);
  k_mean<<<32, 256, 0, stream>>>(scoreb, out);
}

// Round 2
// 861.312 us; speedup vs baseline: 1.0502x; 1.0502x over previous
//
#include <hip/hip_runtime.h>
#include <math.h>

typedef unsigned short u16;
typedef float f32x4 __attribute__((ext_vector_type(4)));
typedef short bf16x8 __attribute__((ext_vector_type(8)));

#define NVIEW 6

// ---------- helpers ----------
__device__ __forceinline__ u16 f2bf(float f){
  unsigned u = __float_as_uint(f);
  u += 0x7FFFu + ((u >> 16) & 1u);      // round-to-nearest-even
  return (u16)(u >> 16);
}
__device__ __forceinline__ float bf2f(u16 h){
  return __uint_as_float(((unsigned)h) << 16);
}
__device__ __forceinline__ float fsig(float x){
  x = fminf(fmaxf(x, -30.f), 30.f);
  return 1.0f / (1.0f + __expf(-x));
}
__device__ __forceinline__ float ftanh(float x){
  x = fminf(fmaxf(x, -15.f), 15.f);
  float e = __expf(2.0f * x);
  return (e - 1.0f) / (e + 1.0f);
}
__device__ __forceinline__ void gload16(const u16* g, u16* l){
  __builtin_amdgcn_global_load_lds((const __attribute__((address_space(1))) unsigned int*)g,
                                   (__attribute__((address_space(3))) unsigned int*)l,
                                   16, 0, 0);
}

// ---------- setup kernels ----------
__global__ void k_cvt(const float* __restrict__ in, u16* __restrict__ out, long n4){
  long i = (long)blockIdx.x * blockDim.x + threadIdx.x;
  long stride = (long)gridDim.x * blockDim.x;
  for (; i < n4; i += stride){
    const float4 v = ((const float4*)in)[i];
    ushort4 o;
    o.x = f2bf(v.x); o.y = f2bf(v.y); o.z = f2bf(v.z); o.w = f2bf(v.w);
    ((ushort4*)out)[i] = o;
  }
}

// Wl[l][4u+q][k] = (k<256 ? Wih[l][q*256+u][k] : Whh[l][q*256+u][k-256]) as bf16
__global__ void k_build_wl(const float* __restrict__ Wih, const float* __restrict__ Whh,
                           u16* __restrict__ Wl){
  int idx = blockIdx.x * 256 + threadIdx.x;   // exactly 3*1024*512 threads
  int l   = idx >> 19;
  int rem = idx & 524287;
  int ro  = rem >> 9;       // interleaved out-row 0..1023
  int k   = rem & 511;
  int u = ro >> 2, q = ro & 3;
  int ri = q * 256 + u;
  float v = (k < 256) ? Wih[(l * 1024 + ri) * 256 + k]
                      : Whh[(l * 1024 + ri) * 256 + (k - 256)];
  Wl[idx] = f2bf(v);
}

__global__ void k_build_bias(const float* __restrict__ bih, const float* __restrict__ bhh,
                             float* __restrict__ biasL, u16* __restrict__ zbuf){
  int idx = blockIdx.x * 256 + threadIdx.x;
  if (idx < 3072){
    int l = idx >> 10; int ro = idx & 1023;
    int u = ro >> 2, q = ro & 3;
    int ri = q * 256 + u;
    biasL[idx] = bih[l * 1024 + ri] + bhh[l * 1024 + ri];
  }
  if (idx < 256) zbuf[idx] = 0;
}

// =====================================================================
// 8-phase 256x256 GEMM (T1+T2+T3+T4+T5): C[m,n] = sum_k A[m,k]*B[n,k]
// 512 threads = 8 waves (2M x 4N). Per-wave interleaved tiling:
//   A row(mf) = mf*32 + wm*16 + l15  (mf 0..7)
//   B row(nf) = nf*64 + wn*16 + l15  (nf 0..3)
// so quadrant (mh,nh) touches only A-half mh / B-half nh of the K-tile.
// LDS 128 KiB: shA[2][256][64], shB[2][256][64], XOR-swizzled content:
//   slot s of row r holds source col16 = s ^ (r&7)  (written via permuted
//   per-lane GLOBAL source, linear LDS dest — rule 21).
// Schedule per iter (2 K-tiles t0=buf0, t1=buf1), stages 1 half/phase:
//   ph1:(0,0)buf0 +stage buf1.B0(t1)   ph2:(1,0) +buf1.A1(t1)
//   ph3:(0,1) +buf0.B0(t0+2)           ph4:(1,1) +buf0.A0(t0+2)  vmcnt(4)*
//   ph5:(0,0)buf1 +buf0.A1(t0+2)       ph6:(0,1) +buf0.B1(t0+2)
//   ph7:(1,1) +buf1.A0(t1+2)           ph8:(1,0) +buf1.B1(t1+2)  vmcnt(4)
// *last iter uses vmcnt(0) (its ph3/4 stages are skipped -> counted wait
//  would under-guarantee t1's B0/A1).
// EPI 0: out = bf16(gelu(acc+bias[n]) + resid[m*N+n]);  EPI 1: bf16(acc+bias)
// =====================================================================
template<int EPI>
__global__ __launch_bounds__(512, 2)
void gemm8p(const u16* __restrict__ A, long sA,
            const u16* __restrict__ Bm, long sB,
            int N, int K,
            const float* __restrict__ bias,
            const float* __restrict__ resid,
            u16* __restrict__ outb)
{
  __shared__ __align__(16) u16 shA[2 * 16384];
  __shared__ __align__(16) u16 shB[2 * 16384];

  const int tid  = threadIdx.x;
  const int lane = tid & 63;
  const int wv   = tid >> 6;           // 0..7
  const int wm   = wv >> 2;            // 0..1
  const int wn   = wv & 3;             // 0..3
  const int wm16 = wm * 16, wn16 = wn * 16;
  const int l15  = lane & 15, lk = lane >> 4;
  const int w2   = wv * 2;

  // XCD-aware swizzle (grid divisible by 8: 768 / 192)
  const int nwg = gridDim.x;
  const int qq  = nwg >> 3;
  const int b   = blockIdx.x;
  const int swz = (b & 7) * qq + (b >> 3);
  const int NB  = N >> 8;
  const long m0 = (long)(swz / NB) * 256;
  const int  n0 = (swz % NB) * 256;

  const int NT = K >> 6;

  // per-lane swizzled global source offset: row += lane>>3, col16 = (lane&7)^(lane>>3)
  const long laneA = (long)(lane >> 3) * sA + (long)(((lane & 7) ^ (lane >> 3)) << 3);
  const long laneB = (long)(lane >> 3) * sB + (long)(((lane & 7) ^ (lane >> 3)) << 3);

  auto STA = [&](int buf, int mh, int t){
    if (t < NT){
      #pragma unroll
      for (int j = 0; j < 2; ++j){
        const int chunk = w2 + j;   // 0..15, 8 rows each
        gload16(A + (m0 + mh * 128 + chunk * 8) * sA + (long)t * 64 + laneA,
                shA + buf * 16384 + mh * 8192 + chunk * 512 + lane * 8);
      }
    }
  };
  auto STB = [&](int buf, int nh, int t){
    if (t < NT){
      #pragma unroll
      for (int j = 0; j < 2; ++j){
        const int chunk = w2 + j;
        gload16(Bm + (long)(n0 + nh * 128 + chunk * 8) * sB + (long)t * 64 + laneB,
                shB + buf * 16384 + nh * 8192 + chunk * 512 + lane * 8);
      }
    }
  };

  f32x4 acc[8][4];
  #pragma unroll
  for (int i = 0; i < 8; ++i)
    #pragma unroll
    for (int j = 0; j < 4; ++j)
      acc[i][j] = (f32x4){0.f, 0.f, 0.f, 0.f};

  // ---- prologue: tile0 (all 4 halves) + tile1.A0 + tile1.B1 ----
  STA(0, 0, 0); STB(0, 0, 0); STA(0, 1, 0); STB(0, 1, 0);
  STA(1, 0, 1); STB(1, 1, 1);
  asm volatile("s_waitcnt vmcnt(4)" ::: "memory");   // tile0 fully landed
  asm volatile("s_barrier" ::: "memory");

#define PH(BUF, MH, NH, STG, VM)                                              \
  {                                                                           \
    bf16x8 af[2][4], bq[2][2];                                                \
    _Pragma("unroll") for (int ks = 0; ks < 2; ++ks){                         \
      _Pragma("unroll") for (int i = 0; i < 4; ++i){                          \
        const int row  = ((MH) * 4 + i) * 32 + wm16 + l15;                    \
        const int slot = (ks * 4 + lk) ^ (l15 & 7);                           \
        af[ks][i] = *(const bf16x8*)&shA[(BUF) * 16384 + row * 64 + slot * 8];\
      }                                                                       \
      _Pragma("unroll") for (int j = 0; j < 2; ++j){                          \
        const int rn   = ((NH) * 2 + j) * 64 + wn16 + l15;                    \
        const int slot = (ks * 4 + lk) ^ (l15 & 7);                           \
        bq[ks][j] = *(const bf16x8*)&shB[(BUF) * 16384 + rn * 64 + slot * 8]; \
      }                                                                       \
    }                                                                         \
    STG;                                                                      \
    asm volatile("s_barrier" ::: "memory");                                   \
    asm volatile("s_waitcnt lgkmcnt(0)" ::: "memory");                        \
    __builtin_amdgcn_s_setprio(1);                                            \
    _Pragma("unroll") for (int i = 0; i < 4; ++i)                             \
      _Pragma("unroll") for (int j = 0; j < 2; ++j)                           \
        _Pragma("unroll") for (int ks = 0; ks < 2; ++ks)                      \
          acc[(MH)*4 + i][(NH)*2 + j] = __builtin_amdgcn_mfma_f32_16x16x32_bf16( \
              af[ks][i], bq[ks][j], acc[(MH)*4 + i][(NH)*2 + j], 0, 0, 0);    \
    __builtin_amdgcn_s_setprio(0);                                            \
    VM;                                                                       \
    asm volatile("s_barrier" ::: "memory");                                   \
  }

  const int NIT = NT >> 1;
  for (int it = 0; it < NIT; ++it){
    const int t1 = 2 * it + 1;
    const bool lastit = (it == NIT - 1);
    PH(0, 0, 0, STB(1, 0, t1), ;);
    PH(0, 1, 0, STA(1, 1, t1), ;);
    PH(0, 0, 1, STB(0, 0, t1 + 1), ;);
    PH(0, 1, 1, STA(0, 0, t1 + 1),
       if (lastit) { asm volatile("s_waitcnt vmcnt(0)" ::: "memory"); }
       else        { asm volatile("s_waitcnt vmcnt(4)" ::: "memory"); });
    PH(1, 0, 0, STA(0, 1, t1 + 1), ;);
    PH(1, 0, 1, STB(0, 1, t1 + 1), ;);
    PH(1, 1, 1, STA(1, 0, t1 + 2), ;);
    PH(1, 1, 0, STB(1, 1, t1 + 2),
       asm volatile("s_waitcnt vmcnt(4)" ::: "memory"););
  }
#undef PH

  // ---- epilogue ----
  #pragma unroll
  for (int mf = 0; mf < 8; ++mf){
    #pragma unroll
    for (int nf = 0; nf < 4; ++nf){
      const int n = n0 + nf * 64 + wn16 + l15;
      const float bz = bias[n];
      const long mrow = m0 + mf * 32 + wm16 + lk * 4;
      #pragma unroll
      for (int r = 0; r < 4; ++r){
        float v = acc[mf][nf][r] + bz;
        const long off = (mrow + r) * (long)N + n;
        if (EPI == 0){
          float ge = 0.5f * v * (1.0f + erff(v * 0.70710678118654752f));
          v = ge + resid[off];
        }
        outb[off] = f2bf(v);
      }
    }
  }
}

// ---------- LSTM GEMM (m97-structure, EPI2 fused cell) — unchanged ----------
template<int EPI>
__global__ __launch_bounds__(256)
void gemm_bt(const u16* __restrict__ A0, long sA0,
             const u16* __restrict__ A1, long sA1, int K0,
             const u16* __restrict__ Bm,
             int N, int K,
             const float* __restrict__ bias,
             const float* __restrict__ resid,
             u16* __restrict__ outb,
             float* __restrict__ cbuf,
             int tstep)
{
  __shared__ __align__(16) u16 lA[128 * 64];
  __shared__ __align__(16) u16 lB[128 * 64];

  const int tid  = threadIdx.x;
  const int lane = tid & 63;
  const int wid  = tid >> 6;
  const int wm = wid >> 1, wn = wid & 1;
  const int l15 = lane & 15, lk = lane >> 4;
  const long m0 = (long)blockIdx.x * 128;
  const int  n0 = blockIdx.y * 128;

  f32x4 acc[4][4];
  #pragma unroll
  for (int i = 0; i < 4; ++i)
    #pragma unroll
    for (int j = 0; j < 4; ++j)
      acc[i][j] = (f32x4){0.f, 0.f, 0.f, 0.f};

  const int rowL = tid >> 3;
  const int col8 = (tid & 7) * 8;

  for (int kt = 0; kt < (K >> 6); ++kt){
    const int kbase = kt << 6;
    #pragma unroll
    for (int c = 0; c < 4; ++c){
      int r = c * 32 + rowL;
      int k = kbase + col8;
      const u16* src = (k < K0) ? (A0 + (m0 + r) * sA0 + k)
                                : (A1 + (m0 + r) * sA1 + (k - K0));
      gload16(src, &lA[r * 64 + col8]);
    }
    #pragma unroll
    for (int c = 0; c < 4; ++c){
      int r = c * 32 + rowL;
      int k = kbase + col8;
      gload16(Bm + (long)(n0 + r) * K + k, &lB[r * 64 + col8]);
    }
    __syncthreads();

    #pragma unroll
    for (int ks = 0; ks < 2; ++ks){
      bf16x8 af[4], bfr[4];
      #pragma unroll
      for (int mf = 0; mf < 4; ++mf)
        af[mf] = *(const bf16x8*)&lA[(wm * 64 + mf * 16 + l15) * 64 + ks * 32 + lk * 8];
      #pragma unroll
      for (int nf = 0; nf < 4; ++nf)
        bfr[nf] = *(const bf16x8*)&lB[(wn * 64 + nf * 16 + l15) * 64 + ks * 32 + lk * 8];
      #pragma unroll
      for (int mf = 0; mf < 4; ++mf)
        #pragma unroll
        for (int nf = 0; nf < 4; ++nf)
          acc[mf][nf] = __builtin_amdgcn_mfma_f32_16x16x32_bf16(af[mf], bfr[nf], acc[mf][nf], 0, 0, 0);
    }
    __syncthreads();
  }

  if (EPI == 0 || EPI == 1){
    #pragma unroll
    for (int mf = 0; mf < 4; ++mf){
      #pragma unroll
      for (int nf = 0; nf < 4; ++nf){
        int  n    = n0 + wn * 64 + nf * 16 + l15;
        long mrow = m0 + wm * 64 + mf * 16 + lk * 4;
        float bz = bias[n];
        #pragma unroll
        for (int r = 0; r < 4; ++r){
          float v = acc[mf][nf][r] + bz;
          long off = (mrow + r) * N + n;
          if (EPI == 0){
            float ge = 0.5f * v * (1.0f + erff(v * 0.70710678118654752f));
            v = ge + resid[off];
          }
          outb[off] = f2bf(v);
        }
      }
    }
  } else {
    const int a  = lane & 3;
    const int qb = lane & ~3;
    #pragma unroll
    for (int mf = 0; mf < 4; ++mf){
      #pragma unroll
      for (int nf = 0; nf < 4; ++nf){
        int n = n0 + wn * 64 + nf * 16 + l15;
        float bz = bias[n];
        float v0 = acc[mf][nf][0] + bz;
        float v1 = acc[mf][nf][1] + bz;
        float v2 = acc[mf][nf][2] + bz;
        float v3 = acc[mf][nf][3] + bz;
        float s0 = (a == 0) ? v0 : (a == 1) ? v1 : (a == 2) ? v2 : v3;
        float s1 = (a == 0) ? v1 : (a == 1) ? v2 : (a == 2) ? v3 : v0;
        float s2 = (a == 0) ? v2 : (a == 1) ? v3 : (a == 2) ? v0 : v1;
        float s3 = (a == 0) ? v3 : (a == 1) ? v0 : (a == 2) ? v1 : v2;
        float r0 = s0;
        float r1 = __shfl(s1, qb + ((a + 3) & 3));
        float r2 = __shfl(s2, qb + ((a + 2) & 3));
        float r3 = __shfl(s3, qb + ((a + 1) & 3));
        float wi = (a == 0) ? r0 : (a == 1) ? r1 : (a == 2) ? r2 : r3;
        float wf = (a == 1) ? r0 : (a == 2) ? r1 : (a == 3) ? r2 : r3;
        float wg = (a == 2) ? r0 : (a == 3) ? r1 : (a == 0) ? r2 : r3;
        float wo = (a == 3) ? r0 : (a == 0) ? r1 : (a == 1) ? r2 : r3;
        long row = m0 + wm * 64 + mf * 16 + lk * 4 + a;
        int  u   = ((n0 + wn * 64 + nf * 16) >> 2) + (l15 >> 2);
        float c_old = (tstep == 0) ? 0.0f : cbuf[row * 256 + u];
        float ii = fsig(wi), ff = fsig(wf), gg = ftanh(wg), oo = fsig(wo);
        float cn = ff * c_old + ii * gg;
        float hn = oo * ftanh(cn);
        cbuf[row * 256 + u] = cn;
        outb[(row * NVIEW + tstep) * 256 + u] = f2bf(hn);
      }
    }
  }
}

// ---------- tail: viewport + score + mean ----------
__global__ void k_score(const u16* __restrict__ X3, const float* __restrict__ Wv,
                        const float* __restrict__ bv, const float* __restrict__ Ws,
                        const float* __restrict__ bs, float* __restrict__ score){
  int lane = threadIdx.x & 63;
  int bm = blockIdx.x * 4 + (threadIdx.x >> 6);
  const u16* row = X3 + (long)bm * (NVIEW * 256);
  float4 wv = *(const float4*)(Wv + lane * 4);
  float p = 0.f;
  #pragma unroll
  for (int n = 0; n < NVIEW; ++n){
    ushort4 xv = *(const ushort4*)(row + n * 256 + lane * 4);
    float d = bf2f(xv.x) * wv.x + bf2f(xv.y) * wv.y + bf2f(xv.z) * wv.z + bf2f(xv.w) * wv.w;
    p += Ws[n] * d;
  }
  #pragma unroll
  for (int off = 32; off; off >>= 1) p += __shfl_xor(p, off);
  if (lane == 0){
    float sw = Ws[0] + Ws[1] + Ws[2] + Ws[3] + Ws[4] + Ws[5];
    score[bm] = p + bv[0] * sw + bs[0];
  }
}

__global__ void k_mean(const float* __restrict__ score, float* __restrict__ out){
  __shared__ float red[256];
  int b = blockIdx.x, tid = threadIdx.x;
  red[tid] = score[b * 256 + tid];
  __syncthreads();
  for (int s = 128; s > 0; s >>= 1){
    if (tid < s) red[tid] += red[tid + s];
    __syncthreads();
  }
  if (tid == 0) out[b] = red[0] * (1.0f / 256.0f);
}

// ---------- launcher ----------
extern "C" void kernel_launch(void* const* d_in, const int* in_sizes, int n_in,
                              void* d_out, int out_size, void* d_ws, size_t ws_size,
                              hipStream_t stream){
  const float* swin = (const float*)d_in[0];
  const float* conv = (const float*)d_in[1];
  const float* Wc   = (const float*)d_in[2];
  const float* bc   = (const float*)d_in[3];
  const float* Win  = (const float*)d_in[4];
  const float* b_in = (const float*)d_in[5];
  const float* Wih  = (const float*)d_in[6];
  const float* Whh  = (const float*)d_in[7];
  const float* bih  = (const float*)d_in[8];
  const float* bhh  = (const float*)d_in[9];
  const float* Wv   = (const float*)d_in[10];
  const float* bv   = (const float*)d_in[11];
  const float* Ws   = (const float*)d_in[12];
  const float* bs   = (const float*)d_in[13];
  float* out = (float*)d_out;

  // workspace layout (~207 MB total)
  char* w = (char*)d_ws;
  u16*  convb = (u16*)(w);                    // 100,663,296 B  [49152*1024] bf16
  u16*  X0    = (u16*)(w);                    // reuses convb region after G1
  u16*  XA    = (u16*)(w + 25165824);
  u16*  XB    = (u16*)(w + 50331648);
  float* cbuf = (float*)(w + 75497472);
  u16*  Y     = (u16*)(w + 100663296);        // 100,663,296
  u16*  Wcb   = (u16*)(w + 201326592);
  u16*  Winb  = (u16*)(w + 203423744);
  u16*  Wl    = (u16*)(w + 203948032);
  float* biasL= (float*)(w + 207093760);
  u16*  zbuf  = (u16*)(w + 207106048);
  float* scoreb = (float*)(w + 207106560);

  // 1) converts + weight transforms
  k_cvt<<<4096, 256, 0, stream>>>(conv, convb, 49152L * 1024 / 4);
  k_cvt<<<512, 256, 0, stream>>>(Wc, Wcb, 1048576 / 4);
  k_cvt<<<128, 256, 0, stream>>>(Win, Winb, 262144 / 4);
  k_build_wl<<<6144, 256, 0, stream>>>(Wih, Whh, Wl);
  k_build_bias<<<12, 256, 0, stream>>>(bih, bhh, biasL, zbuf);

  // 2) G1 (8-phase): Y = bf16( gelu(conv @ Wc^T + bc) + swin )  [49152 x 1024]
  gemm8p<0><<<768, 512, 0, stream>>>(convb, 1024L, Wcb, 1024L,
                                     1024, 1024, bc, swin, Y);

  // 3) G2 (8-phase): X0 = bf16( Y @ Win^T + b_in )              [49152 x 256]
  gemm8p<1><<<192, 512, 0, stream>>>(Y, 1024L, Winb, 1024L,
                                     256, 1024, b_in, (const float*)nullptr, X0);

  // 4) LSTM: 3 layers x 6 timesteps; gates = [x_t, h_{t-1}] @ Wl^T + bias (K=512)
  const u16* xin = X0;
  u16* xout = XA;
  for (int l = 0; l < 3; ++l){
    for (int t = 0; t < 6; ++t){
      const u16* a1 = (t == 0) ? zbuf : (xout + (t - 1) * 256);
      long s1 = (t == 0) ? 0L : 1536L;
      gemm_bt<2><<<dim3(64, 8), 256, 0, stream>>>(
          xin + t * 256, 1536L, a1, s1, 256,
          Wl + l * 1024 * 512, 1024, 512,
          biasL + l * 1024, (const float*)nullptr,
          xout, cbuf, t);
    }
    if (l == 0){ xin = XA; xout = XB; }
    else if (l == 1){ xin = XB; xout = XA; }
  }

  // 5) viewport + score + mean
  k_score<<<2048, 256, 0, stream>>>(XA, Wv, bv, Ws, bs, scoreb);
  k_mean<<<32, 256, 0, stream>>>(scoreb, out);
}

// Round 3
// 857.647 us; speedup vs baseline: 1.0547x; 1.0043x over previous
//
#include <hip/hip_runtime.h>
#include <math.h>
#include <stdint.h>

typedef unsigned short u16;
typedef float f32x4 __attribute__((ext_vector_type(4)));
typedef short bf16x8 __attribute__((ext_vector_type(8)));

#define NVIEW 6

// ---------- helpers ----------
__device__ __forceinline__ u16 f2bf(float f){
  unsigned u = __float_as_uint(f);
  u += 0x7FFFu + ((u >> 16) & 1u);      // round-to-nearest-even
  return (u16)(u >> 16);
}
__device__ __forceinline__ float bf2f(u16 h){
  return __uint_as_float(((unsigned)h) << 16);
}
__device__ __forceinline__ float fsig(float x){
  x = fminf(fmaxf(x, -30.f), 30.f);
  return 1.0f / (1.0f + __expf(-x));
}
__device__ __forceinline__ float ftanh(float x){
  x = fminf(fmaxf(x, -15.f), 15.f);
  float e = __expf(2.0f * x);
  return (e - 1.0f) / (e + 1.0f);
}
__device__ __forceinline__ void gload16(const u16* g, u16* l){
  __builtin_amdgcn_global_load_lds((const __attribute__((address_space(1))) unsigned int*)g,
                                   (__attribute__((address_space(3))) unsigned int*)l,
                                   16, 0, 0);
}

// ---------- setup kernels ----------
__global__ void k_cvt(const float* __restrict__ in, u16* __restrict__ out, long n4){
  long i = (long)blockIdx.x * blockDim.x + threadIdx.x;
  long stride = (long)gridDim.x * blockDim.x;
  for (; i < n4; i += stride){
    const float4 v = ((const float4*)in)[i];
    ushort4 o;
    o.x = f2bf(v.x); o.y = f2bf(v.y); o.z = f2bf(v.z); o.w = f2bf(v.w);
    ((ushort4*)out)[i] = o;
  }
}

// Wl[l][4u+q][k] = (k<256 ? Wih[l][q*256+u][k] : Whh[l][q*256+u][k-256]) as bf16
__global__ void k_build_wl(const float* __restrict__ Wih, const float* __restrict__ Whh,
                           u16* __restrict__ Wl){
  int idx = blockIdx.x * 256 + threadIdx.x;   // exactly 3*1024*512 threads
  int l   = idx >> 19;
  int rem = idx & 524287;
  int ro  = rem >> 9;       // interleaved out-row 0..1023
  int k   = rem & 511;
  int u = ro >> 2, q = ro & 3;
  int ri = q * 256 + u;
  float v = (k < 256) ? Wih[(l * 1024 + ri) * 256 + k]
                      : Whh[(l * 1024 + ri) * 256 + (k - 256)];
  Wl[idx] = f2bf(v);
}

__global__ void k_build_bias(const float* __restrict__ bih, const float* __restrict__ bhh,
                             float* __restrict__ biasL, u16* __restrict__ zbuf){
  int idx = blockIdx.x * 256 + threadIdx.x;
  if (idx < 3072){
    int l = idx >> 10; int ro = idx & 1023;
    int u = ro >> 2, q = ro & 3;
    int ri = q * 256 + u;
    biasL[idx] = bih[l * 1024 + ri] + bhh[l * 1024 + ri];
  }
  if (idx < 256) zbuf[idx] = 0;
}

// =====================================================================
// 8-phase 256x256 GEMM, inline-asm ds_read variant.
// C[m,n] = sum_k A[m,k]*B[n,k]  (B given as [N][K], bf16)
// 512 threads = 8 waves (2M x 4N); per-wave interleaved tiling:
//   A row(mf) = mf*32 + wm*16 + l15; B row(nf) = nf*64 + wn*16 + l15.
// LDS: shA[2][256][64], shB[2][256][64] (bf16), XOR-swizzled content:
//   slot s (16B units) of row r holds source col16 = s ^ (r&7)
//   (written via permuted per-lane GLOBAL source, linear LDS dest — rule 21;
//    read via swizzled inline-asm ds_read_b128 — hidden from the compiler's
//    LDS-DMA alias machinery so no per-phase vmcnt drains get inserted).
// Counted vmcnt(4) at phases 4/8 only; last iteration peeled with vmcnt(0).
// =====================================================================
#define DSR(dst, addr) asm volatile("ds_read_b128 %0, %1" : "=v"(dst) : "v"(addr))
#define VM4 asm volatile("s_waitcnt vmcnt(4)" ::: "memory")
#define VM0 asm volatile("s_waitcnt vmcnt(0)" ::: "memory")

template<int EPI>
__global__ __launch_bounds__(512, 2)
void gemm8p(const u16* __restrict__ A, long sA,
            const u16* __restrict__ Bm, long sB,
            int N, int K,
            const float* __restrict__ bias,
            const float* __restrict__ resid,
            u16* __restrict__ outb)
{
  __shared__ __align__(128) u16 shA[2 * 16384];
  __shared__ __align__(128) u16 shB[2 * 16384];

  const int tid  = threadIdx.x;
  const int lane = tid & 63;
  const int wv   = tid >> 6;           // 0..7
  const int wm   = wv >> 2;            // 0..1
  const int wn   = wv & 3;             // 0..3
  const int wm16 = wm * 16, wn16 = wn * 16;
  const int l15  = lane & 15, lk = lane >> 4;
  const int w2   = wv * 2;

  // XCD-aware swizzle (grid divisible by 8: 768 / 192)
  const int nwg = gridDim.x;
  const int qq  = nwg >> 3;
  const int b   = blockIdx.x;
  const int swz = (b & 7) * qq + (b >> 3);
  const int NB  = N >> 8;
  const long m0 = (long)(swz / NB) * 256;
  const int  n0 = (swz % NB) * 256;

  const int NT  = K >> 6;
  const int NIT = NT >> 1;

  // per-lane swizzled global source offset: row += lane>>3, col16 = (lane&7)^(lane>>3)
  const long laneA = (long)(lane >> 3) * sA + (long)(((lane & 7) ^ (lane >> 3)) << 3);
  const long laneB = (long)(lane >> 3) * sB + (long)(((lane & 7) ^ (lane >> 3)) << 3);

  auto STA = [&](int buf, int mh, int t){
    #pragma unroll
    for (int j = 0; j < 2; ++j){
      const int chunk = w2 + j;   // 0..15, 8 rows each
      gload16(A + (m0 + mh * 128 + chunk * 8) * sA + (long)t * 64 + laneA,
              shA + buf * 16384 + mh * 8192 + chunk * 512 + lane * 8);
    }
  };
  auto STB = [&](int buf, int nh, int t){
    #pragma unroll
    for (int j = 0; j < 2; ++j){
      const int chunk = w2 + j;
      gload16(Bm + (long)(n0 + nh * 128 + chunk * 8) * sB + (long)t * 64 + laneB,
              shB + buf * 16384 + nh * 8192 + chunk * 512 + lane * 8);
    }
  };

  // LDS byte addresses for swizzled ds_read (slot = lk ^ (l15&7); row*128B)
  const unsigned ldsA = (unsigned)(uintptr_t)&shA[0];
  const unsigned ldsB = (unsigned)(uintptr_t)&shB[0];
  const unsigned aAr  = ldsA + (unsigned)((wm16 + l15) * 128 + ((lk ^ (l15 & 7)) << 4));
  const unsigned aBr  = ldsB + (unsigned)((wn16 + l15) * 128 + ((lk ^ (l15 & 7)) << 4));

  f32x4 acc[8][4];
  #pragma unroll
  for (int i = 0; i < 8; ++i)
    #pragma unroll
    for (int j = 0; j < 4; ++j)
      acc[i][j] = (f32x4){0.f, 0.f, 0.f, 0.f};

  // ---- prologue: tile0 (all 4 halves) + tile1.A0 + tile1.B1 ----
  STA(0, 0, 0); STB(0, 0, 0); STA(0, 1, 0); STB(0, 1, 0);
  STA(1, 0, 1); STB(1, 1, 1);
  VM4;                                    // tile0 fully landed (8 oldest done)
  __builtin_amdgcn_s_barrier();

  // one phase: asm ds_reads -> stage -> barrier -> lgkm(0)+schedfence -> MFMA -> VM -> barrier
#define PH(BUF, MH, NH, STG, VM)                                              \
  {                                                                           \
    bf16x8 af[2][4], bq[2][2];                                                \
    const unsigned bA  = aAr + ((BUF) * 32768 + (MH) * 16384);                \
    const unsigned bAx = bA ^ 64;                                             \
    const unsigned bB  = aBr + ((BUF) * 32768 + (NH) * 16384);                \
    const unsigned bBx = bB ^ 64;                                             \
    _Pragma("unroll") for (int i = 0; i < 4; ++i){                            \
      DSR(af[0][i], bA  + i * 4096);                                          \
      DSR(af[1][i], bAx + i * 4096);                                          \
    }                                                                         \
    _Pragma("unroll") for (int j = 0; j < 2; ++j){                            \
      DSR(bq[0][j], bB  + j * 8192);                                          \
      DSR(bq[1][j], bBx + j * 8192);                                          \
    }                                                                         \
    STG;                                                                      \
    __builtin_amdgcn_s_barrier();                                             \
    asm volatile("s_waitcnt lgkmcnt(0)" ::: "memory");                        \
    __builtin_amdgcn_sched_barrier(0);  /* rule #18: fence MFMA hoisting */   \
    __builtin_amdgcn_s_setprio(1);                                            \
    _Pragma("unroll") for (int i = 0; i < 4; ++i)                             \
      _Pragma("unroll") for (int j = 0; j < 2; ++j)                           \
        _Pragma("unroll") for (int ks = 0; ks < 2; ++ks)                      \
          acc[(MH)*4 + i][(NH)*2 + j] = __builtin_amdgcn_mfma_f32_16x16x32_bf16( \
              af[ks][i], bq[ks][j], acc[(MH)*4 + i][(NH)*2 + j], 0, 0, 0);    \
    __builtin_amdgcn_s_setprio(0);                                            \
    VM;                                                                       \
    __builtin_amdgcn_s_barrier();                                             \
  }

  for (int it = 0; it < NIT - 1; ++it){
    const int t1 = 2 * it + 1;
    PH(0, 0, 0, STB(1, 0, t1),     (void)0);
    PH(0, 1, 0, STA(1, 1, t1),     (void)0);
    PH(0, 0, 1, STB(0, 0, t1 + 1), (void)0);
    PH(0, 1, 1, STA(0, 0, t1 + 1), VM4);
    PH(1, 0, 0, STA(0, 1, t1 + 1), (void)0);
    PH(1, 0, 1, STB(0, 1, t1 + 1), (void)0);
    PH(1, 1, 1, STA(1, 0, t1 + 2), (void)0);
    PH(1, 1, 0, STB(1, 1, t1 + 2), VM4);
  }
  // peeled last iteration (t1 = NT-1): only the two buf1 stages remain
  {
    const int t1 = NT - 1;
    PH(0, 0, 0, STB(1, 0, t1), (void)0);
    PH(0, 1, 0, STA(1, 1, t1), (void)0);
    PH(0, 0, 1, (void)0,       (void)0);
    PH(0, 1, 1, (void)0,       VM0);
    PH(1, 0, 0, (void)0,       (void)0);
    PH(1, 0, 1, (void)0,       (void)0);
    PH(1, 1, 1, (void)0,       (void)0);
    PH(1, 1, 0, (void)0,       (void)0);
  }
#undef PH

  // ---- epilogue ----
  #pragma unroll
  for (int mf = 0; mf < 8; ++mf){
    #pragma unroll
    for (int nf = 0; nf < 4; ++nf){
      const int n = n0 + nf * 64 + wn16 + l15;
      const float bz = bias[n];
      const long mrow = m0 + mf * 32 + wm16 + lk * 4;
      #pragma unroll
      for (int r = 0; r < 4; ++r){
        float v = acc[mf][nf][r] + bz;
        const long off = (mrow + r) * (long)N + n;
        if (EPI == 0){
          float ge = 0.5f * v * (1.0f + erff(v * 0.70710678118654752f));
          v = ge + resid[off];
        }
        outb[off] = f2bf(v);
      }
    }
  }
}

// ---------- LSTM GEMM (m97-structure, EPI2 fused cell) — unchanged ----------
template<int EPI>
__global__ __launch_bounds__(256)
void gemm_bt(const u16* __restrict__ A0, long sA0,
             const u16* __restrict__ A1, long sA1, int K0,
             const u16* __restrict__ Bm,
             int N, int K,
             const float* __restrict__ bias,
             const float* __restrict__ resid,
             u16* __restrict__ outb,
             float* __restrict__ cbuf,
             int tstep)
{
  __shared__ __align__(16) u16 lA[128 * 64];
  __shared__ __align__(16) u16 lB[128 * 64];

  const int tid  = threadIdx.x;
  const int lane = tid & 63;
  const int wid  = tid >> 6;
  const int wm = wid >> 1, wn = wid & 1;
  const int l15 = lane & 15, lk = lane >> 4;
  const long m0 = (long)blockIdx.x * 128;
  const int  n0 = blockIdx.y * 128;

  f32x4 acc[4][4];
  #pragma unroll
  for (int i = 0; i < 4; ++i)
    #pragma unroll
    for (int j = 0; j < 4; ++j)
      acc[i][j] = (f32x4){0.f, 0.f, 0.f, 0.f};

  const int rowL = tid >> 3;
  const int col8 = (tid & 7) * 8;

  for (int kt = 0; kt < (K >> 6); ++kt){
    const int kbase = kt << 6;
    #pragma unroll
    for (int c = 0; c < 4; ++c){
      int r = c * 32 + rowL;
      int k = kbase + col8;
      const u16* src = (k < K0) ? (A0 + (m0 + r) * sA0 + k)
                                : (A1 + (m0 + r) * sA1 + (k - K0));
      gload16(src, &lA[r * 64 + col8]);
    }
    #pragma unroll
    for (int c = 0; c < 4; ++c){
      int r = c * 32 + rowL;
      int k = kbase + col8;
      gload16(Bm + (long)(n0 + r) * K + k, &lB[r * 64 + col8]);
    }
    __syncthreads();

    #pragma unroll
    for (int ks = 0; ks < 2; ++ks){
      bf16x8 af[4], bfr[4];
      #pragma unroll
      for (int mf = 0; mf < 4; ++mf)
        af[mf] = *(const bf16x8*)&lA[(wm * 64 + mf * 16 + l15) * 64 + ks * 32 + lk * 8];
      #pragma unroll
      for (int nf = 0; nf < 4; ++nf)
        bfr[nf] = *(const bf16x8*)&lB[(wn * 64 + nf * 16 + l15) * 64 + ks * 32 + lk * 8];
      #pragma unroll
      for (int mf = 0; mf < 4; ++mf)
        #pragma unroll
        for (int nf = 0; nf < 4; ++nf)
          acc[mf][nf] = __builtin_amdgcn_mfma_f32_16x16x32_bf16(af[mf], bfr[nf], acc[mf][nf], 0, 0, 0);
    }
    __syncthreads();
  }

  if (EPI == 0 || EPI == 1){
    #pragma unroll
    for (int mf = 0; mf < 4; ++mf){
      #pragma unroll
      for (int nf = 0; nf < 4; ++nf){
        int  n    = n0 + wn * 64 + nf * 16 + l15;
        long mrow = m0 + wm * 64 + mf * 16 + lk * 4;
        float bz = bias[n];
        #pragma unroll
        for (int r = 0; r < 4; ++r){
          float v = acc[mf][nf][r] + bz;
          long off = (mrow + r) * N + n;
          if (EPI == 0){
            float ge = 0.5f * v * (1.0f + erff(v * 0.70710678118654752f));
            v = ge + resid[off];
          }
          outb[off] = f2bf(v);
        }
      }
    }
  } else {
    const int a  = lane & 3;
    const int qb = lane & ~3;
    #pragma unroll
    for (int mf = 0; mf < 4; ++mf){
      #pragma unroll
      for (int nf = 0; nf < 4; ++nf){
        int n = n0 + wn * 64 + nf * 16 + l15;
        float bz = bias[n];
        float v0 = acc[mf][nf][0] + bz;
        float v1 = acc[mf][nf][1] + bz;
        float v2 = acc[mf][nf][2] + bz;
        float v3 = acc[mf][nf][3] + bz;
        float s0 = (a == 0) ? v0 : (a == 1) ? v1 : (a == 2) ? v2 : v3;
        float s1 = (a == 0) ? v1 : (a == 1) ? v2 : (a == 2) ? v3 : v0;
        float s2 = (a == 0) ? v2 : (a == 1) ? v3 : (a == 2) ? v0 : v1;
        float s3 = (a == 0) ? v3 : (a == 1) ? v0 : (a == 2) ? v1 : v2;
        float r0 = s0;
        float r1 = __shfl(s1, qb + ((a + 3) & 3));
        float r2 = __shfl(s2, qb + ((a + 2) & 3));
        float r3 = __shfl(s3, qb + ((a + 1) & 3));
        float wi = (a == 0) ? r0 : (a == 1) ? r1 : (a == 2) ? r2 : r3;
        float wf = (a == 1) ? r0 : (a == 2) ? r1 : (a == 3) ? r2 : r3;
        float wg = (a == 2) ? r0 : (a == 3) ? r1 : (a == 0) ? r2 : r3;
        float wo = (a == 3) ? r0 : (a == 0) ? r1 : (a == 1) ? r2 : r3;
        long row = m0 + wm * 64 + mf * 16 + lk * 4 + a;
        int  u   = ((n0 + wn * 64 + nf * 16) >> 2) + (l15 >> 2);
        float c_old = (tstep == 0) ? 0.0f : cbuf[row * 256 + u];
        float ii = fsig(wi), ff = fsig(wf), gg = ftanh(wg), oo = fsig(wo);
        float cn = ff * c_old + ii * gg;
        float hn = oo * ftanh(cn);
        cbuf[row * 256 + u] = cn;
        outb[(row * NVIEW + tstep) * 256 + u] = f2bf(hn);
      }
    }
  }
}

// ---------- tail: viewport + score + mean ----------
__global__ void k_score(const u16* __restrict__ X3, const float* __restrict__ Wv,
                        const float* __restrict__ bv, const float* __restrict__ Ws,
                        const float* __restrict__ bs, float* __restrict__ score){
  int lane = threadIdx.x & 63;
  int bm = blockIdx.x * 4 + (threadIdx.x >> 6);
  const u16* row = X3 + (long)bm * (NVIEW * 256);
  float4 wv = *(const float4*)(Wv + lane * 4);
  float p = 0.f;
  #pragma unroll
  for (int n = 0; n < NVIEW; ++n){
    ushort4 xv = *(const ushort4*)(row + n * 256 + lane * 4);
    float d = bf2f(xv.x) * wv.x + bf2f(xv.y) * wv.y + bf2f(xv.z) * wv.z + bf2f(xv.w) * wv.w;
    p += Ws[n] * d;
  }
  #pragma unroll
  for (int off = 32; off; off >>= 1) p += __shfl_xor(p, off);
  if (lane == 0){
    float sw = Ws[0] + Ws[1] + Ws[2] + Ws[3] + Ws[4] + Ws[5];
    score[bm] = p + bv[0] * sw + bs[0];
  }
}

__global__ void k_mean(const float* __restrict__ score, float* __restrict__ out){
  __shared__ float red[256];
  int b = blockIdx.x, tid = threadIdx.x;
  red[tid] = score[b * 256 + tid];
  __syncthreads();
  for (int s = 128; s > 0; s >>= 1){
    if (tid < s) red[tid] += red[tid + s];
    __syncthreads();
  }
  if (tid == 0) out[b] = red[0] * (1.0f / 256.0f);
}

// ---------- launcher ----------
extern "C" void kernel_launch(void* const* d_in, const int* in_sizes, int n_in,
                              void* d_out, int out_size, void* d_ws, size_t ws_size,
                              hipStream_t stream){
  const float* swin = (const float*)d_in[0];
  const float* conv = (const float*)d_in[1];
  const float* Wc   = (const float*)d_in[2];
  const float* bc   = (const float*)d_in[3];
  const float* Win  = (const float*)d_in[4];
  const float* b_in = (const float*)d_in[5];
  const float* Wih  = (const float*)d_in[6];
  const float* Whh  = (const float*)d_in[7];
  const float* bih  = (const float*)d_in[8];
  const float* bhh  = (const float*)d_in[9];
  const float* Wv   = (const float*)d_in[10];
  const float* bv   = (const float*)d_in[11];
  const float* Ws   = (const float*)d_in[12];
  const float* bs   = (const float*)d_in[13];
  float* out = (float*)d_out;

  // workspace layout (~207 MB total)
  char* w = (char*)d_ws;
  u16*  convb = (u16*)(w);                    // 100,663,296 B  [49152*1024] bf16
  u16*  X0    = (u16*)(w);                    // reuses convb region after G1
  u16*  XA    = (u16*)(w + 25165824);
  u16*  XB    = (u16*)(w + 50331648);
  float* cbuf = (float*)(w + 75497472);
  u16*  Y     = (u16*)(w + 100663296);        // 100,663,296
  u16*  Wcb   = (u16*)(w + 201326592);
  u16*  Winb  = (u16*)(w + 203423744);
  u16*  Wl    = (u16*)(w + 203948032);
  float* biasL= (float*)(w + 207093760);
  u16*  zbuf  = (u16*)(w + 207106048);
  float* scoreb = (float*)(w + 207106560);

  // 1) converts + weight transforms
  k_cvt<<<4096, 256, 0, stream>>>(conv, convb, 49152L * 1024 / 4);
  k_cvt<<<512, 256, 0, stream>>>(Wc, Wcb, 1048576 / 4);
  k_cvt<<<128, 256, 0, stream>>>(Win, Winb, 262144 / 4);
  k_build_wl<<<6144, 256, 0, stream>>>(Wih, Whh, Wl);
  k_build_bias<<<12, 256, 0, stream>>>(bih, bhh, biasL, zbuf);

  // 2) G1 (8-phase): Y = bf16( gelu(conv @ Wc^T + bc) + swin )  [49152 x 1024]
  gemm8p<0><<<768, 512, 0, stream>>>(convb, 1024L, Wcb, 1024L,
                                     1024, 1024, bc, swin, Y);

  // 3) G2 (8-phase): X0 = bf16( Y @ Win^T + b_in )              [49152 x 256]
  gemm8p<1><<<192, 512, 0, stream>>>(Y, 1024L, Winb, 1024L,
                                     256, 1024, b_in, (const float*)nullptr, X0);

  // 4) LSTM: 3 layers x 6 timesteps; gates = [x_t, h_{t-1}] @ Wl^T + bias (K=512)
  const u16* xin = X0;
  u16* xout = XA;
  for (int l = 0; l < 3; ++l){
    for (int t = 0; t < 6; ++t){
      const u16* a1 = (t == 0) ? zbuf : (xout + (t - 1) * 256);
      long s1 = (t == 0) ? 0L : 1536L;
      gemm_bt<2><<<dim3(64, 8), 256, 0, stream>>>(
          xin + t * 256, 1536L, a1, s1, 256,
          Wl + l * 1024 * 512, 1024, 512,
          biasL + l * 1024, (const float*)nullptr,
          xout, cbuf, t);
    }
    if (l == 0){ xin = XA; xout = XB; }
    else if (l == 1){ xin = XB; xout = XA; }
  }

  // 5) viewport + score + mean
  k_score<<<2048, 256, 0, stream>>>(XA, Wv, bv, Ws, bs, scoreb);
  k_mean<<<32, 256, 0, stream>>>(scoreb, out);
}

// Round 4
// 831.728 us; speedup vs baseline: 1.0876x; 1.0312x over previous
//
#include <hip/hip_runtime.h>
#include <math.h>
#include <stdint.h>

typedef unsigned short u16;
typedef float f32x4 __attribute__((ext_vector_type(4)));
typedef short bf16x8 __attribute__((ext_vector_type(8)));

#define NVIEW 6

// ---------- helpers ----------
__device__ __forceinline__ u16 f2bf(float f){
  unsigned u = __float_as_uint(f);
  u += 0x7FFFu + ((u >> 16) & 1u);      // round-to-nearest-even
  return (u16)(u >> 16);
}
__device__ __forceinline__ float bf2f(u16 h){
  return __uint_as_float(((unsigned)h) << 16);
}
__device__ __forceinline__ float fsig(float x){
  x = fminf(fmaxf(x, -30.f), 30.f);
  return 1.0f / (1.0f + __expf(-x));
}
__device__ __forceinline__ float ftanh(float x){
  x = fminf(fmaxf(x, -15.f), 15.f);
  float e = __expf(2.0f * x);
  return (e - 1.0f) / (e + 1.0f);
}
__device__ __forceinline__ void gload16(const u16* g, u16* l){
  __builtin_amdgcn_global_load_lds((const __attribute__((address_space(1))) unsigned int*)g,
                                   (__attribute__((address_space(3))) unsigned int*)l,
                                   16, 0, 0);
}

// ---------- setup kernels ----------
__global__ void k_cvt(const float* __restrict__ in, u16* __restrict__ out, long n4){
  long i = (long)blockIdx.x * blockDim.x + threadIdx.x;
  long stride = (long)gridDim.x * blockDim.x;
  for (; i < n4; i += stride){
    const float4 v = ((const float4*)in)[i];
    ushort4 o;
    o.x = f2bf(v.x); o.y = f2bf(v.y); o.z = f2bf(v.z); o.w = f2bf(v.w);
    ((ushort4*)out)[i] = o;
  }
}

// Wl[l][4u+q][k] = (k<256 ? Wih[l][q*256+u][k] : Whh[l][q*256+u][k-256]) as bf16
__global__ void k_build_wl(const float* __restrict__ Wih, const float* __restrict__ Whh,
                           u16* __restrict__ Wl){
  int idx = blockIdx.x * 256 + threadIdx.x;   // exactly 3*1024*512 threads
  int l   = idx >> 19;
  int rem = idx & 524287;
  int ro  = rem >> 9;       // interleaved out-row 0..1023
  int k   = rem & 511;
  int u = ro >> 2, q = ro & 3;
  int ri = q * 256 + u;
  float v = (k < 256) ? Wih[(l * 1024 + ri) * 256 + k]
                      : Whh[(l * 1024 + ri) * 256 + (k - 256)];
  Wl[idx] = f2bf(v);
}

__global__ void k_build_bias(const float* __restrict__ bih, const float* __restrict__ bhh,
                             float* __restrict__ biasL, u16* __restrict__ zbuf){
  int idx = blockIdx.x * 256 + threadIdx.x;
  if (idx < 3072){
    int l = idx >> 10; int ro = idx & 1023;
    int u = ro >> 2, q = ro & 3;
    int ri = q * 256 + u;
    biasL[idx] = bih[l * 1024 + ri] + bhh[l * 1024 + ri];
  }
  if (idx < 256) zbuf[idx] = 0;
}

// =====================================================================
// 2-phase 256x256 GEMM, ONE barrier + ONE vmcnt per K-tile.
// C[m,n] = sum_k A[m,k]*B[n,k]  (B given as [N][K], bf16)
// 512 threads = 8 waves (2M x 4N); per-wave 128x64 output:
//   A row(mf) = mf*32 + wm*16 + l15 (mf 0..7); B row(nf) = nf*64 + wn*16 + l15.
// LDS: shA[2][256][64], shB[2][256][64] bf16 (128 KiB), XOR-swizzled content
//   (slot s of row r holds source col16 s^(r&7); staged via permuted global
//    source + linear LDS dest — rule 21).
// Per K-tile body:
//   vmcnt(0)   <- waits for THIS tile's stage, issued one full tile earlier
//   barrier    <- after it, all waves' reads of buf^1 (tile t-1) are done
//   STAGE(t+1) into buf^1 (safe: nobody reads it anymore)
//   24 ds_read (ks0 set then ks1 set), frags held in registers
//   lgkm(12) -> 32 MFMA(ks0);  lgkm(0) -> 32 MFMA(ks1)
// Reads once per tile (24 KB/wave) — half the 8-phase traffic; 1 barrier/tile.
// EPI 0: out = bf16(gelu(acc+bias[n]) + resid[m*N+n]);  EPI 1: bf16(acc+bias)
// =====================================================================
#define DSR(dst, addr) asm volatile("ds_read_b128 %0, %1" : "=v"(dst) : "v"(addr))

template<int EPI>
__global__ __launch_bounds__(512, 2)
void gemm2p(const u16* __restrict__ A, long sA,
            const u16* __restrict__ Bm, long sB,
            int N, int K,
            const float* __restrict__ bias,
            const float* __restrict__ resid,
            u16* __restrict__ outb)
{
  __shared__ __align__(128) u16 shA[2 * 16384];
  __shared__ __align__(128) u16 shB[2 * 16384];

  const int tid  = threadIdx.x;
  const int lane = tid & 63;
  const int wv   = tid >> 6;           // 0..7
  const int wm   = wv >> 2;            // 0..1
  const int wn   = wv & 3;             // 0..3
  const int wm16 = wm * 16, wn16 = wn * 16;
  const int l15  = lane & 15, lk = lane >> 4;
  const int w2   = wv * 2;

  // XCD-aware swizzle (grids used are divisible by 8)
  const int nwg = gridDim.x;
  const int qq  = nwg >> 3;
  const int b   = blockIdx.x;
  const int swz = (b & 7) * qq + (b >> 3);
  const int NB  = N >> 8;
  const long m0 = (long)(swz / NB) * 256;
  const int  n0 = (swz % NB) * 256;

  const int NT = K >> 6;

  // per-lane swizzled global source: row += lane>>3, col16 = (lane&7)^(lane>>3)
  const long laneA = (long)(lane >> 3) * sA + (long)(((lane & 7) ^ (lane >> 3)) << 3);
  const long laneB = (long)(lane >> 3) * sB + (long)(((lane & 7) ^ (lane >> 3)) << 3);

  auto STAGE = [&](int buf, int t){
    #pragma unroll
    for (int mh = 0; mh < 2; ++mh)
      #pragma unroll
      for (int j = 0; j < 2; ++j){
        const int chunk = w2 + j;   // 0..15, 8 rows each
        gload16(A + (m0 + mh * 128 + chunk * 8) * sA + (long)t * 64 + laneA,
                shA + buf * 16384 + mh * 8192 + chunk * 512 + lane * 8);
      }
    #pragma unroll
    for (int nh = 0; nh < 2; ++nh)
      #pragma unroll
      for (int j = 0; j < 2; ++j){
        const int chunk = w2 + j;
        gload16(Bm + (long)(n0 + nh * 128 + chunk * 8) * sB + (long)t * 64 + laneB,
                shB + buf * 16384 + nh * 8192 + chunk * 512 + lane * 8);
      }
  };

  // LDS byte addresses for swizzled ds_read: row*128B + (slot^(l15&7))*16B
  // slot(ks=0) = lk; slot(ks=1) = lk+4  -> addr(ks1) = addr(ks0) ^ 64
  const unsigned ldsA = (unsigned)(uintptr_t)&shA[0];
  const unsigned ldsB = (unsigned)(uintptr_t)&shB[0];
  const unsigned aA0  = ldsA + (unsigned)((wm16 + l15) * 128 + ((lk ^ (l15 & 7)) << 4));
  const unsigned aB0  = ldsB + (unsigned)((wn16 + l15) * 128 + ((lk ^ (l15 & 7)) << 4));

  f32x4 acc[8][4];
  #pragma unroll
  for (int i = 0; i < 8; ++i)
    #pragma unroll
    for (int j = 0; j < 4; ++j)
      acc[i][j] = (f32x4){0.f, 0.f, 0.f, 0.f};

  // prologue: stage tile 0 into buf 0
  STAGE(0, 0);

  for (int t = 0; t < NT; ++t){
    const int cur = t & 1;
    asm volatile("s_waitcnt vmcnt(0)" ::: "memory");  // tile t landed (issued 1 tile ago)
    __builtin_amdgcn_s_barrier();
    if (t + 1 < NT) STAGE(cur ^ 1, t + 1);

    bf16x8 af[2][8], bq[2][4];
    const unsigned bufOff = (unsigned)(cur * 32768);
    const unsigned aA = aA0 + bufOff, aB = aB0 + bufOff;
    // issue ks0 set (12 reads), then ks1 set (12 reads)
    #pragma unroll
    for (int mf = 0; mf < 8; ++mf) DSR(af[0][mf], aA + mf * 4096);
    #pragma unroll
    for (int nf = 0; nf < 4; ++nf) DSR(bq[0][nf], aB + nf * 8192);
    #pragma unroll
    for (int mf = 0; mf < 8; ++mf) DSR(af[1][mf], (aA ^ 64) + mf * 4096);
    #pragma unroll
    for (int nf = 0; nf < 4; ++nf) DSR(bq[1][nf], (aB ^ 64) + nf * 8192);

    asm volatile("s_waitcnt lgkmcnt(12)" ::: "memory");  // ks0 set done
    __builtin_amdgcn_sched_barrier(0);                   // rule #18
    __builtin_amdgcn_s_setprio(1);
    #pragma unroll
    for (int mf = 0; mf < 8; ++mf)
      #pragma unroll
      for (int nf = 0; nf < 4; ++nf)
        acc[mf][nf] = __builtin_amdgcn_mfma_f32_16x16x32_bf16(af[0][mf], bq[0][nf], acc[mf][nf], 0, 0, 0);
    __builtin_amdgcn_s_setprio(0);

    asm volatile("s_waitcnt lgkmcnt(0)" ::: "memory");   // ks1 set done
    __builtin_amdgcn_sched_barrier(0);
    __builtin_amdgcn_s_setprio(1);
    #pragma unroll
    for (int mf = 0; mf < 8; ++mf)
      #pragma unroll
      for (int nf = 0; nf < 4; ++nf)
        acc[mf][nf] = __builtin_amdgcn_mfma_f32_16x16x32_bf16(af[1][mf], bq[1][nf], acc[mf][nf], 0, 0, 0);
    __builtin_amdgcn_s_setprio(0);
  }

  // ---- epilogue ----
  #pragma unroll
  for (int mf = 0; mf < 8; ++mf){
    #pragma unroll
    for (int nf = 0; nf < 4; ++nf){
      const int n = n0 + nf * 64 + wn16 + l15;
      const float bz = bias[n];
      const long mrow = m0 + mf * 32 + wm16 + lk * 4;
      #pragma unroll
      for (int r = 0; r < 4; ++r){
        float v = acc[mf][nf][r] + bz;
        const long off = (mrow + r) * (long)N + n;
        if (EPI == 0){
          float ge = 0.5f * v * (1.0f + erff(v * 0.70710678118654752f));
          v = ge + resid[off];
        }
        outb[off] = f2bf(v);
      }
    }
  }
}

// ---------- LSTM GEMM (m97-structure, EPI2 fused cell) — unchanged ----------
template<int EPI>
__global__ __launch_bounds__(256)
void gemm_bt(const u16* __restrict__ A0, long sA0,
             const u16* __restrict__ A1, long sA1, int K0,
             const u16* __restrict__ Bm,
             int N, int K,
             const float* __restrict__ bias,
             const float* __restrict__ resid,
             u16* __restrict__ outb,
             float* __restrict__ cbuf,
             int tstep)
{
  __shared__ __align__(16) u16 lA[128 * 64];
  __shared__ __align__(16) u16 lB[128 * 64];

  const int tid  = threadIdx.x;
  const int lane = tid & 63;
  const int wid  = tid >> 6;
  const int wm = wid >> 1, wn = wid & 1;
  const int l15 = lane & 15, lk = lane >> 4;
  const long m0 = (long)blockIdx.x * 128;
  const int  n0 = blockIdx.y * 128;

  f32x4 acc[4][4];
  #pragma unroll
  for (int i = 0; i < 4; ++i)
    #pragma unroll
    for (int j = 0; j < 4; ++j)
      acc[i][j] = (f32x4){0.f, 0.f, 0.f, 0.f};

  const int rowL = tid >> 3;
  const int col8 = (tid & 7) * 8;

  for (int kt = 0; kt < (K >> 6); ++kt){
    const int kbase = kt << 6;
    #pragma unroll
    for (int c = 0; c < 4; ++c){
      int r = c * 32 + rowL;
      int k = kbase + col8;
      const u16* src = (k < K0) ? (A0 + (m0 + r) * sA0 + k)
                                : (A1 + (m0 + r) * sA1 + (k - K0));
      gload16(src, &lA[r * 64 + col8]);
    }
    #pragma unroll
    for (int c = 0; c < 4; ++c){
      int r = c * 32 + rowL;
      int k = kbase + col8;
      gload16(Bm + (long)(n0 + r) * K + k, &lB[r * 64 + col8]);
    }
    __syncthreads();

    #pragma unroll
    for (int ks = 0; ks < 2; ++ks){
      bf16x8 af[4], bfr[4];
      #pragma unroll
      for (int mf = 0; mf < 4; ++mf)
        af[mf] = *(const bf16x8*)&lA[(wm * 64 + mf * 16 + l15) * 64 + ks * 32 + lk * 8];
      #pragma unroll
      for (int nf = 0; nf < 4; ++nf)
        bfr[nf] = *(const bf16x8*)&lB[(wn * 64 + nf * 16 + l15) * 64 + ks * 32 + lk * 8];
      #pragma unroll
      for (int mf = 0; mf < 4; ++mf)
        #pragma unroll
        for (int nf = 0; nf < 4; ++nf)
          acc[mf][nf] = __builtin_amdgcn_mfma_f32_16x16x32_bf16(af[mf], bfr[nf], acc[mf][nf], 0, 0, 0);
    }
    __syncthreads();
  }

  if (EPI == 0 || EPI == 1){
    #pragma unroll
    for (int mf = 0; mf < 4; ++mf){
      #pragma unroll
      for (int nf = 0; nf < 4; ++nf){
        int  n    = n0 + wn * 64 + nf * 16 + l15;
        long mrow = m0 + wm * 64 + mf * 16 + lk * 4;
        float bz = bias[n];
        #pragma unroll
        for (int r = 0; r < 4; ++r){
          float v = acc[mf][nf][r] + bz;
          long off = (mrow + r) * N + n;
          if (EPI == 0){
            float ge = 0.5f * v * (1.0f + erff(v * 0.70710678118654752f));
            v = ge + resid[off];
          }
          outb[off] = f2bf(v);
        }
      }
    }
  } else {
    const int a  = lane & 3;
    const int qb = lane & ~3;
    #pragma unroll
    for (int mf = 0; mf < 4; ++mf){
      #pragma unroll
      for (int nf = 0; nf < 4; ++nf){
        int n = n0 + wn * 64 + nf * 16 + l15;
        float bz = bias[n];
        float v0 = acc[mf][nf][0] + bz;
        float v1 = acc[mf][nf][1] + bz;
        float v2 = acc[mf][nf][2] + bz;
        float v3 = acc[mf][nf][3] + bz;
        float s0 = (a == 0) ? v0 : (a == 1) ? v1 : (a == 2) ? v2 : v3;
        float s1 = (a == 0) ? v1 : (a == 1) ? v2 : (a == 2) ? v3 : v0;
        float s2 = (a == 0) ? v2 : (a == 1) ? v3 : (a == 2) ? v0 : v1;
        float s3 = (a == 0) ? v3 : (a == 1) ? v0 : (a == 2) ? v1 : v2;
        float r0 = s0;
        float r1 = __shfl(s1, qb + ((a + 3) & 3));
        float r2 = __shfl(s2, qb + ((a + 2) & 3));
        float r3 = __shfl(s3, qb + ((a + 1) & 3));
        float wi = (a == 0) ? r0 : (a == 1) ? r1 : (a == 2) ? r2 : r3;
        float wf = (a == 1) ? r0 : (a == 2) ? r1 : (a == 3) ? r2 : r3;
        float wg = (a == 2) ? r0 : (a == 3) ? r1 : (a == 0) ? r2 : r3;
        float wo = (a == 3) ? r0 : (a == 0) ? r1 : (a == 1) ? r2 : r3;
        long row = m0 + wm * 64 + mf * 16 + lk * 4 + a;
        int  u   = ((n0 + wn * 64 + nf * 16) >> 2) + (l15 >> 2);
        float c_old = (tstep == 0) ? 0.0f : cbuf[row * 256 + u];
        float ii = fsig(wi), ff = fsig(wf), gg = ftanh(wg), oo = fsig(wo);
        float cn = ff * c_old + ii * gg;
        float hn = oo * ftanh(cn);
        cbuf[row * 256 + u] = cn;
        outb[(row * NVIEW + tstep) * 256 + u] = f2bf(hn);
      }
    }
  }
}

// ---------- tail: viewport + score + mean ----------
__global__ void k_score(const u16* __restrict__ X3, const float* __restrict__ Wv,
                        const float* __restrict__ bv, const float* __restrict__ Ws,
                        const float* __restrict__ bs, float* __restrict__ score){
  int lane = threadIdx.x & 63;
  int bm = blockIdx.x * 4 + (threadIdx.x >> 6);
  const u16* row = X3 + (long)bm * (NVIEW * 256);
  float4 wv = *(const float4*)(Wv + lane * 4);
  float p = 0.f;
  #pragma unroll
  for (int n = 0; n < NVIEW; ++n){
    ushort4 xv = *(const ushort4*)(row + n * 256 + lane * 4);
    float d = bf2f(xv.x) * wv.x + bf2f(xv.y) * wv.y + bf2f(xv.z) * wv.z + bf2f(xv.w) * wv.w;
    p += Ws[n] * d;
  }
  #pragma unroll
  for (int off = 32; off; off >>= 1) p += __shfl_xor(p, off);
  if (lane == 0){
    float sw = Ws[0] + Ws[1] + Ws[2] + Ws[3] + Ws[4] + Ws[5];
    score[bm] = p + bv[0] * sw + bs[0];
  }
}

__global__ void k_mean(const float* __restrict__ score, float* __restrict__ out){
  __shared__ float red[256];
  int b = blockIdx.x, tid = threadIdx.x;
  red[tid] = score[b * 256 + tid];
  __syncthreads();
  for (int s = 128; s > 0; s >>= 1){
    if (tid < s) red[tid] += red[tid + s];
    __syncthreads();
  }
  if (tid == 0) out[b] = red[0] * (1.0f / 256.0f);
}

// ---------- launcher ----------
extern "C" void kernel_launch(void* const* d_in, const int* in_sizes, int n_in,
                              void* d_out, int out_size, void* d_ws, size_t ws_size,
                              hipStream_t stream){
  const float* swin = (const float*)d_in[0];
  const float* conv = (const float*)d_in[1];
  const float* Wc   = (const float*)d_in[2];
  const float* bc   = (const float*)d_in[3];
  const float* Win  = (const float*)d_in[4];
  const float* b_in = (const float*)d_in[5];
  const float* Wih  = (const float*)d_in[6];
  const float* Whh  = (const float*)d_in[7];
  const float* bih  = (const float*)d_in[8];
  const float* bhh  = (const float*)d_in[9];
  const float* Wv   = (const float*)d_in[10];
  const float* bv   = (const float*)d_in[11];
  const float* Ws   = (const float*)d_in[12];
  const float* bs   = (const float*)d_in[13];
  float* out = (float*)d_out;

  // workspace layout (~207 MB total)
  char* w = (char*)d_ws;
  u16*  convb = (u16*)(w);                    // 100,663,296 B  [49152*1024] bf16
  u16*  X0    = (u16*)(w);                    // reuses convb region after G1
  u16*  XA    = (u16*)(w + 25165824);
  u16*  XB    = (u16*)(w + 50331648);
  float* cbuf = (float*)(w + 75497472);
  u16*  Y     = (u16*)(w + 100663296);        // 100,663,296
  u16*  Wcb   = (u16*)(w + 201326592);
  u16*  Winb  = (u16*)(w + 203423744);
  u16*  Wl    = (u16*)(w + 203948032);
  float* biasL= (float*)(w + 207093760);
  u16*  zbuf  = (u16*)(w + 207106048);
  float* scoreb = (float*)(w + 207106560);

  // 1) converts + weight transforms
  k_cvt<<<4096, 256, 0, stream>>>(conv, convb, 49152L * 1024 / 4);
  k_cvt<<<512, 256, 0, stream>>>(Wc, Wcb, 1048576 / 4);
  k_cvt<<<128, 256, 0, stream>>>(Win, Winb, 262144 / 4);
  k_build_wl<<<6144, 256, 0, stream>>>(Wih, Whh, Wl);
  k_build_bias<<<12, 256, 0, stream>>>(bih, bhh, biasL, zbuf);

  // 2) G1 (2-phase 256²): Y = bf16( gelu(conv @ Wc^T + bc) + swin )  [49152 x 1024]
  gemm2p<0><<<768, 512, 0, stream>>>(convb, 1024L, Wcb, 1024L,
                                     1024, 1024, bc, swin, Y);

  // 3) G2 (2-phase 256²): X0 = bf16( Y @ Win^T + b_in )              [49152 x 256]
  gemm2p<1><<<192, 512, 0, stream>>>(Y, 1024L, Winb, 1024L,
                                     256, 1024, b_in, (const float*)nullptr, X0);

  // 4) LSTM: 3 layers x 6 timesteps; gates = [x_t, h_{t-1}] @ Wl^T + bias (K=512)
  const u16* xin = X0;
  u16* xout = XA;
  for (int l = 0; l < 3; ++l){
    for (int t = 0; t < 6; ++t){
      const u16* a1 = (t == 0) ? zbuf : (xout + (t - 1) * 256);
      long s1 = (t == 0) ? 0L : 1536L;
      gemm_bt<2><<<dim3(64, 8), 256, 0, stream>>>(
          xin + t * 256, 1536L, a1, s1, 256,
          Wl + l * 1024 * 512, 1024, 512,
          biasL + l * 1024, (const float*)nullptr,
          xout, cbuf, t);
    }
    if (l == 0){ xin = XA; xout = XB; }
    else if (l == 1){ xin = XB; xout = XA; }
  }

  // 5) viewport + score + mean
  k_score<<<2048, 256, 0, stream>>>(XA, Wv, bv, Ws, bs, scoreb);
  k_mean<<<32, 256, 0, stream>>>(scoreb, out);
}

// Round 5
// 825.468 us; speedup vs baseline: 1.0958x; 1.0076x over previous
//
#include <hip/hip_runtime.h>
#include <math.h>
#include <stdint.h>

typedef unsigned short u16;
typedef float f32x4 __attribute__((ext_vector_type(4)));
typedef short bf16x8 __attribute__((ext_vector_type(8)));
typedef unsigned short u16x8 __attribute__((ext_vector_type(8)));

#define NVIEW 6

// ---------- helpers ----------
__device__ __forceinline__ u16 f2bf(float f){
  unsigned u = __float_as_uint(f);
  u += 0x7FFFu + ((u >> 16) & 1u);      // round-to-nearest-even
  return (u16)(u >> 16);
}
__device__ __forceinline__ float bf2f(u16 h){
  return __uint_as_float(((unsigned)h) << 16);
}
__device__ __forceinline__ float fsig(float x){
  x = fminf(fmaxf(x, -30.f), 30.f);
  return 1.0f / (1.0f + __expf(-x));
}
__device__ __forceinline__ float ftanh(float x){
  x = fminf(fmaxf(x, -15.f), 15.f);
  float e = __expf(2.0f * x);
  return (e - 1.0f) / (e + 1.0f);
}
__device__ __forceinline__ void gload16(const u16* g, u16* l){
  __builtin_amdgcn_global_load_lds((const __attribute__((address_space(1))) unsigned int*)g,
                                   (__attribute__((address_space(3))) unsigned int*)l,
                                   16, 0, 0);
}

// =====================================================================
// Packed tile-linear layout for gemm2p operands (BM/BN=256, BK=64):
//   slab s = mblk*NT + kt (32 KB each); within slab, element octet at
//   mh*8192 + chunk*512 + lane*8  holds source
//   (row = mblk*256 + mh*128 + chunk*8 + (lane>>3),
//    col = kt*64 + ((lane&7)^(lane>>3))*8 + e)       [XOR swizzle baked in]
// -> gemm2p staging reads are fully CONTIGUOUS (1 KB/instr, 32 KB/tile).
// =====================================================================
__global__ void k_packA(const float* __restrict__ src, u16* __restrict__ dst,
                        int Kdim, long noct){
  const int K8 = Kdim >> 3;
  const int NT = Kdim >> 6;
  long g = (long)blockIdx.x * blockDim.x + threadIdx.x;
  const long stride = (long)gridDim.x * blockDim.x;
  for (; g < noct; g += stride){
    const long m  = g / K8;
    const int  k8 = (int)(g - m * K8);
    const int  k  = k8 << 3;
    const float4* p = (const float4*)(src + m * (long)Kdim + k);
    const float4 v0 = p[0], v1 = p[1];
    const int mblk = (int)(m >> 8), r = (int)(m & 255);
    const int kt = k >> 6, c16 = (k >> 3) & 7;
    const int mh = r >> 7, chunk = (r >> 3) & 15, lnrow = r & 7;
    const int lane = lnrow * 8 + (c16 ^ lnrow);
    const long off = (((long)(mblk * NT + kt) * 2 + mh) << 13) + chunk * 512 + lane * 8;
    u16x8 o;
    o[0] = f2bf(v0.x); o[1] = f2bf(v0.y); o[2] = f2bf(v0.z); o[3] = f2bf(v0.w);
    o[4] = f2bf(v1.x); o[5] = f2bf(v1.y); o[6] = f2bf(v1.z); o[7] = f2bf(v1.w);
    *(u16x8*)(dst + off) = o;
  }
}

// Wl[l][4u+q][k] = (k<256 ? Wih[l][q*256+u][k] : Whh[l][q*256+u][k-256]) as bf16
__global__ void k_build_wl(const float* __restrict__ Wih, const float* __restrict__ Whh,
                           u16* __restrict__ Wl){
  int idx = blockIdx.x * 256 + threadIdx.x;   // exactly 3*1024*512 threads
  int l   = idx >> 19;
  int rem = idx & 524287;
  int ro  = rem >> 9;       // interleaved out-row 0..1023
  int k   = rem & 511;
  int u = ro >> 2, q = ro & 3;
  int ri = q * 256 + u;
  float v = (k < 256) ? Wih[(l * 1024 + ri) * 256 + k]
                      : Whh[(l * 1024 + ri) * 256 + (k - 256)];
  Wl[idx] = f2bf(v);
}

__global__ void k_build_bias(const float* __restrict__ bih, const float* __restrict__ bhh,
                             float* __restrict__ biasL, u16* __restrict__ zbuf){
  int idx = blockIdx.x * 256 + threadIdx.x;
  if (idx < 3072){
    int l = idx >> 10; int ro = idx & 1023;
    int u = ro >> 2, q = ro & 3;
    int ri = q * 256 + u;
    biasL[idx] = bih[l * 1024 + ri] + bhh[l * 1024 + ri];
  }
  if (idx < 256) zbuf[idx] = 0;
}

// =====================================================================
// 2-phase 256x256 GEMM on PACKED operands (one barrier + one vmcnt/K-tile).
// EPI 0: Y(packed) = bf16(gelu(acc+bias[n]) + resid[m*N+n])   (G1)
// EPI 1: out(plain [M][N]) = bf16(acc+bias[n])                 (G2)
// =====================================================================
#define DSR(dst, addr) asm volatile("ds_read_b128 %0, %1" : "=v"(dst) : "v"(addr))

template<int EPI>
__global__ __launch_bounds__(512, 2)
void gemm2p(const u16* __restrict__ A,
            const u16* __restrict__ Bm,
            int N, int K,
            const float* __restrict__ bias,
            const float* __restrict__ resid,
            u16* __restrict__ outb)
{
  __shared__ __align__(128) u16 shA[2 * 16384];
  __shared__ __align__(128) u16 shB[2 * 16384];

  const int tid  = threadIdx.x;
  const int lane = tid & 63;
  const int wv   = tid >> 6;           // 0..7
  const int wm   = wv >> 2;            // 0..1
  const int wn   = wv & 3;             // 0..3
  const int wm16 = wm * 16, wn16 = wn * 16;
  const int l15  = lane & 15, lk = lane >> 4;
  const int w2   = wv * 2;

  // XCD-aware swizzle (grids used are divisible by 8)
  const int nwg = gridDim.x;
  const int qq  = nwg >> 3;
  const int b   = blockIdx.x;
  const int swz = (b & 7) * qq + (b >> 3);
  const int NB  = N >> 8;
  const int mblk = swz / NB;
  const int nblk = swz % NB;
  const long m0 = (long)mblk * 256;
  const int  n0 = nblk * 256;

  const int NT = K >> 6;

  auto STAGE = [&](int buf, int t){
    const u16* baseA = A + (((long)(mblk * NT + t) * 2) << 13);
    const u16* baseB = Bm + (((long)(nblk * NT + t) * 2) << 13);
    #pragma unroll
    for (int mh = 0; mh < 2; ++mh)
      #pragma unroll
      for (int j = 0; j < 2; ++j){
        const int off = (mh << 13) + (w2 + j) * 512 + lane * 8;
        gload16(baseA + off, shA + buf * 16384 + off);
      }
    #pragma unroll
    for (int nh = 0; nh < 2; ++nh)
      #pragma unroll
      for (int j = 0; j < 2; ++j){
        const int off = (nh << 13) + (w2 + j) * 512 + lane * 8;
        gload16(baseB + off, shB + buf * 16384 + off);
      }
  };

  // LDS byte addresses for swizzled ds_read: row*128B + (slot^(l15&7))*16B
  const unsigned ldsA = (unsigned)(uintptr_t)&shA[0];
  const unsigned ldsB = (unsigned)(uintptr_t)&shB[0];
  const unsigned aA0  = ldsA + (unsigned)((wm16 + l15) * 128 + ((lk ^ (l15 & 7)) << 4));
  const unsigned aB0  = ldsB + (unsigned)((wn16 + l15) * 128 + ((lk ^ (l15 & 7)) << 4));

  f32x4 acc[8][4];
  #pragma unroll
  for (int i = 0; i < 8; ++i)
    #pragma unroll
    for (int j = 0; j < 4; ++j)
      acc[i][j] = (f32x4){0.f, 0.f, 0.f, 0.f};

  // prologue: stage tile 0 into buf 0
  STAGE(0, 0);

  for (int t = 0; t < NT; ++t){
    const int cur = t & 1;
    asm volatile("s_waitcnt vmcnt(0)" ::: "memory");  // tile t landed (issued 1 tile ago)
    __builtin_amdgcn_s_barrier();
    if (t + 1 < NT) STAGE(cur ^ 1, t + 1);

    bf16x8 af[2][8], bq[2][4];
    const unsigned bufOff = (unsigned)(cur * 32768);
    const unsigned aA = aA0 + bufOff, aB = aB0 + bufOff;
    #pragma unroll
    for (int mf = 0; mf < 8; ++mf) DSR(af[0][mf], aA + mf * 4096);
    #pragma unroll
    for (int nf = 0; nf < 4; ++nf) DSR(bq[0][nf], aB + nf * 8192);
    #pragma unroll
    for (int mf = 0; mf < 8; ++mf) DSR(af[1][mf], (aA ^ 64) + mf * 4096);
    #pragma unroll
    for (int nf = 0; nf < 4; ++nf) DSR(bq[1][nf], (aB ^ 64) + nf * 8192);

    asm volatile("s_waitcnt lgkmcnt(12)" ::: "memory");  // ks0 set done
    __builtin_amdgcn_sched_barrier(0);                   // rule #18
    __builtin_amdgcn_s_setprio(1);
    #pragma unroll
    for (int mf = 0; mf < 8; ++mf)
      #pragma unroll
      for (int nf = 0; nf < 4; ++nf)
        acc[mf][nf] = __builtin_amdgcn_mfma_f32_16x16x32_bf16(af[0][mf], bq[0][nf], acc[mf][nf], 0, 0, 0);
    __builtin_amdgcn_s_setprio(0);

    asm volatile("s_waitcnt lgkmcnt(0)" ::: "memory");   // ks1 set done
    __builtin_amdgcn_sched_barrier(0);
    __builtin_amdgcn_s_setprio(1);
    #pragma unroll
    for (int mf = 0; mf < 8; ++mf)
      #pragma unroll
      for (int nf = 0; nf < 4; ++nf)
        acc[mf][nf] = __builtin_amdgcn_mfma_f32_16x16x32_bf16(af[1][mf], bq[1][nf], acc[mf][nf], 0, 0, 0);
    __builtin_amdgcn_s_setprio(0);
  }

  // ---- epilogue ----
  #pragma unroll
  for (int mf = 0; mf < 8; ++mf){
    #pragma unroll
    for (int nf = 0; nf < 4; ++nf){
      const int n = n0 + nf * 64 + wn16 + l15;
      const float bz = bias[n];
      const int rloc0 = mf * 32 + wm16 + lk * 4;
      #pragma unroll
      for (int r = 0; r < 4; ++r){
        float v = acc[mf][nf][r] + bz;
        if (EPI == 0){
          // GELU + residual, write Y in PACKED layout (consumed by G2)
          const long roff = (m0 + rloc0 + r) * (long)N + n;
          float ge = 0.5f * v * (1.0f + erff(v * 0.70710678118654752f));
          v = ge + resid[roff];
          const int rloc = rloc0 + r;
          const int kt = n >> 6, c16 = (n >> 3) & 7, e = n & 7;
          const int mh = rloc >> 7, chunk = (rloc >> 3) & 15, lnrow = rloc & 7;
          const long off = (((long)(mblk * NT /*==16: N==K==1024*/ + kt) * 2 + mh) << 13)
                         + chunk * 512 + (lnrow * 8 + (c16 ^ lnrow)) * 8 + e;
          outb[off] = f2bf(v);
        } else {
          const long off = (m0 + rloc0 + r) * (long)N + n;
          outb[off] = f2bf(v);
        }
      }
    }
  }
}

// ---------- LSTM GEMM (m97-structure, EPI2 fused cell) — unchanged ----------
template<int EPI>
__global__ __launch_bounds__(256)
void gemm_bt(const u16* __restrict__ A0, long sA0,
             const u16* __restrict__ A1, long sA1, int K0,
             const u16* __restrict__ Bm,
             int N, int K,
             const float* __restrict__ bias,
             const float* __restrict__ resid,
             u16* __restrict__ outb,
             float* __restrict__ cbuf,
             int tstep)
{
  __shared__ __align__(16) u16 lA[128 * 64];
  __shared__ __align__(16) u16 lB[128 * 64];

  const int tid  = threadIdx.x;
  const int lane = tid & 63;
  const int wid  = tid >> 6;
  const int wm = wid >> 1, wn = wid & 1;
  const int l15 = lane & 15, lk = lane >> 4;
  const long m0 = (long)blockIdx.x * 128;
  const int  n0 = blockIdx.y * 128;

  f32x4 acc[4][4];
  #pragma unroll
  for (int i = 0; i < 4; ++i)
    #pragma unroll
    for (int j = 0; j < 4; ++j)
      acc[i][j] = (f32x4){0.f, 0.f, 0.f, 0.f};

  const int rowL = tid >> 3;
  const int col8 = (tid & 7) * 8;

  for (int kt = 0; kt < (K >> 6); ++kt){
    const int kbase = kt << 6;
    #pragma unroll
    for (int c = 0; c < 4; ++c){
      int r = c * 32 + rowL;
      int k = kbase + col8;
      const u16* src = (k < K0) ? (A0 + (m0 + r) * sA0 + k)
                                : (A1 + (m0 + r) * sA1 + (k - K0));
      gload16(src, &lA[r * 64 + col8]);
    }
    #pragma unroll
    for (int c = 0; c < 4; ++c){
      int r = c * 32 + rowL;
      int k = kbase + col8;
      gload16(Bm + (long)(n0 + r) * K + k, &lB[r * 64 + col8]);
    }
    __syncthreads();

    #pragma unroll
    for (int ks = 0; ks < 2; ++ks){
      bf16x8 af[4], bfr[4];
      #pragma unroll
      for (int mf = 0; mf < 4; ++mf)
        af[mf] = *(const bf16x8*)&lA[(wm * 64 + mf * 16 + l15) * 64 + ks * 32 + lk * 8];
      #pragma unroll
      for (int nf = 0; nf < 4; ++nf)
        bfr[nf] = *(const bf16x8*)&lB[(wn * 64 + nf * 16 + l15) * 64 + ks * 32 + lk * 8];
      #pragma unroll
      for (int mf = 0; mf < 4; ++mf)
        #pragma unroll
        for (int nf = 0; nf < 4; ++nf)
          acc[mf][nf] = __builtin_amdgcn_mfma_f32_16x16x32_bf16(af[mf], bfr[nf], acc[mf][nf], 0, 0, 0);
    }
    __syncthreads();
  }

  if (EPI == 0 || EPI == 1){
    #pragma unroll
    for (int mf = 0; mf < 4; ++mf){
      #pragma unroll
      for (int nf = 0; nf < 4; ++nf){
        int  n    = n0 + wn * 64 + nf * 16 + l15;
        long mrow = m0 + wm * 64 + mf * 16 + lk * 4;
        float bz = bias[n];
        #pragma unroll
        for (int r = 0; r < 4; ++r){
          float v = acc[mf][nf][r] + bz;
          long off = (mrow + r) * N + n;
          if (EPI == 0){
            float ge = 0.5f * v * (1.0f + erff(v * 0.70710678118654752f));
            v = ge + resid[off];
          }
          outb[off] = f2bf(v);
        }
      }
    }
  } else {
    const int a  = lane & 3;
    const int qb = lane & ~3;
    #pragma unroll
    for (int mf = 0; mf < 4; ++mf){
      #pragma unroll
      for (int nf = 0; nf < 4; ++nf){
        int n = n0 + wn * 64 + nf * 16 + l15;
        float bz = bias[n];
        float v0 = acc[mf][nf][0] + bz;
        float v1 = acc[mf][nf][1] + bz;
        float v2 = acc[mf][nf][2] + bz;
        float v3 = acc[mf][nf][3] + bz;
        float s0 = (a == 0) ? v0 : (a == 1) ? v1 : (a == 2) ? v2 : v3;
        float s1 = (a == 0) ? v1 : (a == 1) ? v2 : (a == 2) ? v3 : v0;
        float s2 = (a == 0) ? v2 : (a == 1) ? v3 : (a == 2) ? v0 : v1;
        float s3 = (a == 0) ? v3 : (a == 1) ? v0 : (a == 2) ? v1 : v2;
        float r0 = s0;
        float r1 = __shfl(s1, qb + ((a + 3) & 3));
        float r2 = __shfl(s2, qb + ((a + 2) & 3));
        float r3 = __shfl(s3, qb + ((a + 1) & 3));
        float wi = (a == 0) ? r0 : (a == 1) ? r1 : (a == 2) ? r2 : r3;
        float wf = (a == 1) ? r0 : (a == 2) ? r1 : (a == 3) ? r2 : r3;
        float wg = (a == 2) ? r0 : (a == 3) ? r1 : (a == 0) ? r2 : r3;
        float wo = (a == 3) ? r0 : (a == 0) ? r1 : (a == 1) ? r2 : r3;
        long row = m0 + wm * 64 + mf * 16 + lk * 4 + a;
        int  u   = ((n0 + wn * 64 + nf * 16) >> 2) + (l15 >> 2);
        float c_old = (tstep == 0) ? 0.0f : cbuf[row * 256 + u];
        float ii = fsig(wi), ff = fsig(wf), gg = ftanh(wg), oo = fsig(wo);
        float cn = ff * c_old + ii * gg;
        float hn = oo * ftanh(cn);
        cbuf[row * 256 + u] = cn;
        outb[(row * NVIEW + tstep) * 256 + u] = f2bf(hn);
      }
    }
  }
}

// ---------- tail: viewport + score + mean ----------
__global__ void k_score(const u16* __restrict__ X3, const float* __restrict__ Wv,
                        const float* __restrict__ bv, const float* __restrict__ Ws,
                        const float* __restrict__ bs, float* __restrict__ score){
  int lane = threadIdx.x & 63;
  int bm = blockIdx.x * 4 + (threadIdx.x >> 6);
  const u16* row = X3 + (long)bm * (NVIEW * 256);
  float4 wv = *(const float4*)(Wv + lane * 4);
  float p = 0.f;
  #pragma unroll
  for (int n = 0; n < NVIEW; ++n){
    ushort4 xv = *(const ushort4*)(row + n * 256 + lane * 4);
    float d = bf2f(xv.x) * wv.x + bf2f(xv.y) * wv.y + bf2f(xv.z) * wv.z + bf2f(xv.w) * wv.w;
    p += Ws[n] * d;
  }
  #pragma unroll
  for (int off = 32; off; off >>= 1) p += __shfl_xor(p, off);
  if (lane == 0){
    float sw = Ws[0] + Ws[1] + Ws[2] + Ws[3] + Ws[4] + Ws[5];
    score[bm] = p + bv[0] * sw + bs[0];
  }
}

__global__ void k_mean(const float* __restrict__ score, float* __restrict__ out){
  __shared__ float red[256];
  int b = blockIdx.x, tid = threadIdx.x;
  red[tid] = score[b * 256 + tid];
  __syncthreads();
  for (int s = 128; s > 0; s >>= 1){
    if (tid < s) red[tid] += red[tid + s];
    __syncthreads();
  }
  if (tid == 0) out[b] = red[0] * (1.0f / 256.0f);
}

// ---------- launcher ----------
extern "C" void kernel_launch(void* const* d_in, const int* in_sizes, int n_in,
                              void* d_out, int out_size, void* d_ws, size_t ws_size,
                              hipStream_t stream){
  const float* swin = (const float*)d_in[0];
  const float* conv = (const float*)d_in[1];
  const float* Wc   = (const float*)d_in[2];
  const float* bc   = (const float*)d_in[3];
  const float* Win  = (const float*)d_in[4];
  const float* b_in = (const float*)d_in[5];
  const float* Wih  = (const float*)d_in[6];
  const float* Whh  = (const float*)d_in[7];
  const float* bih  = (const float*)d_in[8];
  const float* bhh  = (const float*)d_in[9];
  const float* Wv   = (const float*)d_in[10];
  const float* bv   = (const float*)d_in[11];
  const float* Ws   = (const float*)d_in[12];
  const float* bs   = (const float*)d_in[13];
  float* out = (float*)d_out;

  // workspace layout (~207 MB total)
  char* w = (char*)d_ws;
  u16*  convP = (u16*)(w);                    // 100,663,296 B  conv packed bf16
  u16*  X0    = (u16*)(w);                    // reuses convP region after G1 (G2 out, plain)
  u16*  XA    = (u16*)(w + 25165824);
  u16*  XB    = (u16*)(w + 50331648);
  float* cbuf = (float*)(w + 75497472);
  u16*  Y     = (u16*)(w + 100663296);        // 100,663,296  Y packed bf16
  u16*  WcP   = (u16*)(w + 201326592);        //  2,097,152
  u16*  WinP  = (u16*)(w + 203423744);        //    524,288
  u16*  Wl    = (u16*)(w + 203948032);        //  3,145,728
  float* biasL= (float*)(w + 207093760);
  u16*  zbuf  = (u16*)(w + 207106048);
  float* scoreb = (float*)(w + 207106560);

  // 1) pack/convert weights + conv activations (tile-linear + XOR swizzle baked)
  k_packA<<<8192, 256, 0, stream>>>(conv, convP, 1024, 49152L * 1024 / 8);
  k_packA<<<512, 256, 0, stream>>>(Wc, WcP, 1024, 1024L * 1024 / 8);
  k_packA<<<128, 256, 0, stream>>>(Win, WinP, 1024, 256L * 1024 / 8);
  k_build_wl<<<6144, 256, 0, stream>>>(Wih, Whh, Wl);
  k_build_bias<<<12, 256, 0, stream>>>(bih, bhh, biasL, zbuf);

  // 2) G1: Y(packed) = bf16( gelu(convP @ WcP^T + bc) + swin )   [49152 x 1024]
  gemm2p<0><<<768, 512, 0, stream>>>(convP, WcP, 1024, 1024, bc, swin, Y);

  // 3) G2: X0(plain) = bf16( Y @ WinP^T + b_in )                 [49152 x 256]
  gemm2p<1><<<192, 512, 0, stream>>>(Y, WinP, 256, 1024, b_in, (const float*)nullptr, X0);

  // 4) LSTM: 3 layers x 6 timesteps; gates = [x_t, h_{t-1}] @ Wl^T + bias (K=512)
  const u16* xin = X0;
  u16* xout = XA;
  for (int l = 0; l < 3; ++l){
    for (int t = 0; t < 6; ++t){
      const u16* a1 = (t == 0) ? zbuf : (xout + (t - 1) * 256);
      long s1 = (t == 0) ? 0L : 1536L;
      gemm_bt<2><<<dim3(64, 8), 256, 0, stream>>>(
          xin + t * 256, 1536L, a1, s1, 256,
          Wl + l * 1024 * 512, 1024, 512,
          biasL + l * 1024, (const float*)nullptr,
          xout, cbuf, t);
    }
    if (l == 0){ xin = XA; xout = XB; }
    else if (l == 1){ xin = XB; xout = XA; }
  }

  // 5) viewport + score + mean
  k_score<<<2048, 256, 0, stream>>>(XA, Wv, bv, Ws, bs, scoreb);
  k_mean<<<32, 256, 0, stream>>>(scoreb, out);
}

// Round 6
// 756.071 us; speedup vs baseline: 1.1964x; 1.0918x over previous
//
#include <hip/hip_runtime.h>
#include <math.h>
#include <stdint.h>

typedef unsigned short u16;
typedef float f32x4 __attribute__((ext_vector_type(4)));
typedef short bf16x8 __attribute__((ext_vector_type(8)));

#define NVIEW 6

// ---------- helpers ----------
__device__ __forceinline__ u16 f2bf(float f){
  unsigned u = __float_as_uint(f);
  u += 0x7FFFu + ((u >> 16) & 1u);      // round-to-nearest-even
  return (u16)(u >> 16);
}
__device__ __forceinline__ float bf2f(u16 h){
  return __uint_as_float(((unsigned)h) << 16);
}
__device__ __forceinline__ float fsig(float x){
  x = fminf(fmaxf(x, -30.f), 30.f);
  return 1.0f / (1.0f + __expf(-x));
}
__device__ __forceinline__ float ftanh(float x){
  x = fminf(fmaxf(x, -15.f), 15.f);
  float e = __expf(2.0f * x);
  return (e - 1.0f) / (e + 1.0f);
}
// exact GELU via Abramowitz-Stegun 7.1.26 erf (|err| < 1.5e-7, way under bf16 ulp)
__device__ __forceinline__ float gelu_exact(float v){
  float x  = v * 0.70710678118654752f;
  float ax = fabsf(x);
  float t  = 1.0f / fmaf(0.3275911f, ax, 1.0f);
  float p  = t * fmaf(t, fmaf(t, fmaf(t, fmaf(t, 1.061405429f, -1.453152027f),
                                      1.421413741f), -0.284496736f), 0.254829592f);
  float er = copysignf(1.0f - p * __expf(-ax * ax), x);
  return 0.5f * v * (1.0f + er);
}
__device__ __forceinline__ void gload16(const u16* g, u16* l){
  __builtin_amdgcn_global_load_lds((const __attribute__((address_space(1))) unsigned int*)g,
                                   (__attribute__((address_space(3))) unsigned int*)l,
                                   16, 0, 0);
}

// ---------- setup kernels ----------
__global__ void k_cvt(const float* __restrict__ in, u16* __restrict__ out, long n4){
  long i = (long)blockIdx.x * blockDim.x + threadIdx.x;
  long stride = (long)gridDim.x * blockDim.x;
  for (; i < n4; i += stride){
    const float4 v = ((const float4*)in)[i];
    ushort4 o;
    o.x = f2bf(v.x); o.y = f2bf(v.y); o.z = f2bf(v.z); o.w = f2bf(v.w);
    ((ushort4*)out)[i] = o;
  }
}

// Wl[l][4u+q][k] = (k<256 ? Wih[l][q*256+u][k] : Whh[l][q*256+u][k-256]) as bf16
__global__ void k_build_wl(const float* __restrict__ Wih, const float* __restrict__ Whh,
                           u16* __restrict__ Wl){
  int idx = blockIdx.x * 256 + threadIdx.x;   // exactly 3*1024*512 threads
  int l   = idx >> 19;
  int rem = idx & 524287;
  int ro  = rem >> 9;       // interleaved out-row 0..1023
  int k   = rem & 511;
  int u = ro >> 2, q = ro & 3;
  int ri = q * 256 + u;
  float v = (k < 256) ? Wih[(l * 1024 + ri) * 256 + k]
                      : Whh[(l * 1024 + ri) * 256 + (k - 256)];
  Wl[idx] = f2bf(v);
}

__global__ void k_build_bias(const float* __restrict__ bih, const float* __restrict__ bhh,
                             float* __restrict__ biasL, u16* __restrict__ zbuf){
  int idx = blockIdx.x * 256 + threadIdx.x;
  if (idx < 3072){
    int l = idx >> 10; int ro = idx & 1023;
    int u = ro >> 2, q = ro & 3;
    int ri = q * 256 + u;
    biasL[idx] = bih[l * 1024 + ri] + bhh[l * 1024 + ri];
  }
  if (idx < 256) zbuf[idx] = 0;
}

// =====================================================================
// Deep-ring 128x128 GEMM: C[m,n] = sum_k A[m,k]*B[n,k]  (B is [N][K] bf16)
// 256 threads = 4 waves (2M x 2N), wave tile 64x64, BK = 32.
// LDS: 5-slot ring, lA[5][128*32] + lB[5][128*32] = 80 KB -> 2 blocks/CU.
// Prefetch depth 4 tiles: per tile each thread issues exactly 4 gloads;
// steady-state wait = vmcnt(12) -> waits only on loads issued 4 tiles
// (~10k cyc) earlier, so HBM latency is fully covered. One drain-free
// s_barrier per tile: per-wave vmcnt before it guarantees every wave's
// tile-t LDS writes landed; slot-reuse distance 5 > max inter-wave skew 1.
// LDS swizzle (rule 21): slot s of row r holds source col16 = s ^ (r&3)
// via pre-swizzled GLOBAL source + linear LDS dest; reads XOR back.
// A split in K: cols [0,K0) from A0 (stride sA0), [K0,K) from A1 (sA1).
// EPI 0: out = bf16(gelu_exact(acc+bias[n]) + resid[m*N+n])
// EPI 1: out = bf16(acc+bias[n])
// EPI 2: fused LSTM cell (gate-interleaved N=1024), h->outb, c<->cbuf.
// =====================================================================
template<int EPI>
__global__ __launch_bounds__(256, 2)
void gemm_dr(const u16* __restrict__ A0, long sA0,
             const u16* __restrict__ A1, long sA1, int K0,
             const u16* __restrict__ Bm, long sB,
             int N, int K,
             const float* __restrict__ bias,
             const float* __restrict__ resid,
             u16* __restrict__ outb,
             float* __restrict__ cbuf,
             int tstep)
{
  __shared__ __align__(16) u16 lA[5 * 4096];
  __shared__ __align__(16) u16 lB[5 * 4096];

  const int tid  = threadIdx.x;
  const int lane = tid & 63;
  const int wid  = tid >> 6;
  const int wm = wid >> 1, wn = wid & 1;
  const int l15 = lane & 15, lk = lane >> 4;
  const long m0 = (long)blockIdx.x * 128;
  const int  n0 = blockIdx.y * 128;
  const int  NT = K >> 5;

  // staging mapping: thread -> (rows c*64 + rA0, col16 cA), swizzled source
  const int rA0  = tid >> 2;            // 0..63
  const int cA   = tid & 3;             // 0..3
  const int scol = (cA ^ (rA0 & 3)) << 3;   // swizzled source column (elements)
  const int ldst = rA0 * 32 + cA * 8;       // linear LDS dest (u16), == base+lane*8

  auto STAGE = [&](int slot, int t){
    const int kb = t << 5;
    const int so = slot * 4096;
    #pragma unroll
    for (int c = 0; c < 2; ++c){
      const int r  = c * 64 + rA0;
      const int gc = kb + scol;
      const u16* s = (gc < K0) ? (A0 + (m0 + r) * sA0 + gc)
                               : (A1 + (m0 + r) * sA1 + (gc - K0));
      gload16(s, &lA[so + c * 2048 + ldst]);
    }
    #pragma unroll
    for (int c = 0; c < 2; ++c){
      const int r = c * 64 + rA0;
      gload16(Bm + (long)(n0 + r) * sB + (kb + scol), &lB[so + c * 2048 + ldst]);
    }
  };

  f32x4 acc[4][4];
  #pragma unroll
  for (int i = 0; i < 4; ++i)
    #pragma unroll
    for (int j = 0; j < 4; ++j)
      acc[i][j] = (f32x4){0.f, 0.f, 0.f, 0.f};

  // read offsets: row*64B + swizzled 16B slot
  const int rdA = (wm * 64 + l15) * 32 + ((lk ^ (l15 & 3)) << 3);
  const int rdB = (wn * 64 + l15) * 32 + ((lk ^ (l15 & 3)) << 3);

  auto COMPUTE = [&](int slot){
    const int so = slot * 4096;
    bf16x8 af[4], bq[4];
    #pragma unroll
    for (int mf = 0; mf < 4; ++mf)
      af[mf] = *(const bf16x8*)&lA[so + rdA + mf * 512];
    #pragma unroll
    for (int nf = 0; nf < 4; ++nf)
      bq[nf] = *(const bf16x8*)&lB[so + rdB + nf * 512];
    #pragma unroll
    for (int mf = 0; mf < 4; ++mf)
      #pragma unroll
      for (int nf = 0; nf < 4; ++nf)
        acc[mf][nf] = __builtin_amdgcn_mfma_f32_16x16x32_bf16(af[mf], bq[nf], acc[mf][nf], 0, 0, 0);
  };

  // prologue: fill 4 ring slots
  STAGE(0, 0); STAGE(1, 1); STAGE(2, 2); STAGE(3, 3);

  int sr = 0, sw = 4;
  for (int t = 0; t + 4 <= NT; ++t){          // t = 0 .. NT-4
    asm volatile("s_waitcnt vmcnt(12)" ::: "memory");
    asm volatile("s_barrier" ::: "memory");
    if (t + 4 < NT){ STAGE(sw, t + 4); }
    COMPUTE(sr);
    sr = (sr == 4) ? 0 : sr + 1;
    sw = (sw == 4) ? 0 : sw + 1;
  }
  asm volatile("s_waitcnt vmcnt(8)" ::: "memory");
  asm volatile("s_barrier" ::: "memory");
  COMPUTE(sr); sr = (sr == 4) ? 0 : sr + 1;
  asm volatile("s_waitcnt vmcnt(4)" ::: "memory");
  asm volatile("s_barrier" ::: "memory");
  COMPUTE(sr); sr = (sr == 4) ? 0 : sr + 1;
  asm volatile("s_waitcnt vmcnt(0)" ::: "memory");
  asm volatile("s_barrier" ::: "memory");
  COMPUTE(sr);

  // ---- epilogue ----
  if (EPI == 0 || EPI == 1){
    #pragma unroll
    for (int mf = 0; mf < 4; ++mf){
      #pragma unroll
      for (int nf = 0; nf < 4; ++nf){
        int  n    = n0 + wn * 64 + nf * 16 + l15;
        long mrow = m0 + wm * 64 + mf * 16 + lk * 4;
        float bz = bias[n];
        #pragma unroll
        for (int r = 0; r < 4; ++r){
          float v = acc[mf][nf][r] + bz;
          long off = (mrow + r) * N + n;
          if (EPI == 0) v = gelu_exact(v) + resid[off];
          outb[off] = f2bf(v);
        }
      }
    }
  } else {
    // LSTM cell epilogue. D-frag: row=(lane>>4)*4+reg, col=lane&15.
    // Quad lanes hold gates i,f,g,o of unit u=n>>2; 4x4 quad transpose.
    const int a  = lane & 3;
    const int qb = lane & ~3;
    #pragma unroll
    for (int mf = 0; mf < 4; ++mf){
      #pragma unroll
      for (int nf = 0; nf < 4; ++nf){
        int n = n0 + wn * 64 + nf * 16 + l15;
        float bz = bias[n];
        float v0 = acc[mf][nf][0] + bz;
        float v1 = acc[mf][nf][1] + bz;
        float v2 = acc[mf][nf][2] + bz;
        float v3 = acc[mf][nf][3] + bz;
        float s0 = (a == 0) ? v0 : (a == 1) ? v1 : (a == 2) ? v2 : v3;
        float s1 = (a == 0) ? v1 : (a == 1) ? v2 : (a == 2) ? v3 : v0;
        float s2 = (a == 0) ? v2 : (a == 1) ? v3 : (a == 2) ? v0 : v1;
        float s3 = (a == 0) ? v3 : (a == 1) ? v0 : (a == 2) ? v1 : v2;
        float r0 = s0;
        float r1 = __shfl(s1, qb + ((a + 3) & 3));
        float r2 = __shfl(s2, qb + ((a + 2) & 3));
        float r3 = __shfl(s3, qb + ((a + 1) & 3));
        float wi = (a == 0) ? r0 : (a == 1) ? r1 : (a == 2) ? r2 : r3;
        float wf = (a == 1) ? r0 : (a == 2) ? r1 : (a == 3) ? r2 : r3;
        float wg = (a == 2) ? r0 : (a == 3) ? r1 : (a == 0) ? r2 : r3;
        float wo = (a == 3) ? r0 : (a == 0) ? r1 : (a == 1) ? r2 : r3;
        long row = m0 + wm * 64 + mf * 16 + lk * 4 + a;
        int  u   = ((n0 + wn * 64 + nf * 16) >> 2) + (l15 >> 2);
        float c_old = (tstep == 0) ? 0.0f : cbuf[row * 256 + u];
        float ii = fsig(wi), ff = fsig(wf), gg = ftanh(wg), oo = fsig(wo);
        float cn = ff * c_old + ii * gg;
        float hn = oo * ftanh(cn);
        cbuf[row * 256 + u] = cn;
        outb[(row * NVIEW + tstep) * 256 + u] = f2bf(hn);
      }
    }
  }
}

// ---------- tail: viewport + score + mean ----------
__global__ void k_score(const u16* __restrict__ X3, const float* __restrict__ Wv,
                        const float* __restrict__ bv, const float* __restrict__ Ws,
                        const float* __restrict__ bs, float* __restrict__ score){
  int lane = threadIdx.x & 63;
  int bm = blockIdx.x * 4 + (threadIdx.x >> 6);
  const u16* row = X3 + (long)bm * (NVIEW * 256);
  float4 wv = *(const float4*)(Wv + lane * 4);
  float p = 0.f;
  #pragma unroll
  for (int n = 0; n < NVIEW; ++n){
    ushort4 xv = *(const ushort4*)(row + n * 256 + lane * 4);
    float d = bf2f(xv.x) * wv.x + bf2f(xv.y) * wv.y + bf2f(xv.z) * wv.z + bf2f(xv.w) * wv.w;
    p += Ws[n] * d;
  }
  #pragma unroll
  for (int off = 32; off; off >>= 1) p += __shfl_xor(p, off);
  if (lane == 0){
    float sw = Ws[0] + Ws[1] + Ws[2] + Ws[3] + Ws[4] + Ws[5];
    score[bm] = p + bv[0] * sw + bs[0];
  }
}

__global__ void k_mean(const float* __restrict__ score, float* __restrict__ out){
  __shared__ float red[256];
  int b = blockIdx.x, tid = threadIdx.x;
  red[tid] = score[b * 256 + tid];
  __syncthreads();
  for (int s = 128; s > 0; s >>= 1){
    if (tid < s) red[tid] += red[tid + s];
    __syncthreads();
  }
  if (tid == 0) out[b] = red[0] * (1.0f / 256.0f);
}

// ---------- launcher ----------
extern "C" void kernel_launch(void* const* d_in, const int* in_sizes, int n_in,
                              void* d_out, int out_size, void* d_ws, size_t ws_size,
                              hipStream_t stream){
  const float* swin = (const float*)d_in[0];
  const float* conv = (const float*)d_in[1];
  const float* Wc   = (const float*)d_in[2];
  const float* bc   = (const float*)d_in[3];
  const float* Win  = (const float*)d_in[4];
  const float* b_in = (const float*)d_in[5];
  const float* Wih  = (const float*)d_in[6];
  const float* Whh  = (const float*)d_in[7];
  const float* bih  = (const float*)d_in[8];
  const float* bhh  = (const float*)d_in[9];
  const float* Wv   = (const float*)d_in[10];
  const float* bv   = (const float*)d_in[11];
  const float* Ws   = (const float*)d_in[12];
  const float* bs   = (const float*)d_in[13];
  float* out = (float*)d_out;

  // workspace layout (~207 MB total)
  char* w = (char*)d_ws;
  u16*  convb = (u16*)(w);                    // 100,663,296 B  [49152*1024] bf16
  u16*  X0    = (u16*)(w);                    // reuses convb region after G1
  u16*  XA    = (u16*)(w + 25165824);
  u16*  XB    = (u16*)(w + 50331648);
  float* cbuf = (float*)(w + 75497472);
  u16*  Y     = (u16*)(w + 100663296);        // 100,663,296  (plain [49152][1024])
  u16*  Wcb   = (u16*)(w + 201326592);
  u16*  Winb  = (u16*)(w + 203423744);
  u16*  Wl    = (u16*)(w + 203948032);
  float* biasL= (float*)(w + 207093760);
  u16*  zbuf  = (u16*)(w + 207106048);
  float* scoreb = (float*)(w + 207106560);

  // 1) converts + weight transforms
  k_cvt<<<4096, 256, 0, stream>>>(conv, convb, 49152L * 1024 / 4);
  k_cvt<<<512, 256, 0, stream>>>(Wc, Wcb, 1048576 / 4);
  k_cvt<<<128, 256, 0, stream>>>(Win, Winb, 262144 / 4);
  k_build_wl<<<6144, 256, 0, stream>>>(Wih, Whh, Wl);
  k_build_bias<<<12, 256, 0, stream>>>(bih, bhh, biasL, zbuf);

  // 2) G1: Y = bf16( gelu(conv @ Wc^T + bc) + swin )   [49152 x 1024]
  gemm_dr<0><<<dim3(384, 8), 256, 0, stream>>>(
      convb, 1024L, convb, 1024L, 1024,
      Wcb, 1024L, 1024, 1024, bc, swin, Y, (float*)nullptr, 0);

  // 3) G2: X0 = bf16( Y @ Win^T + b_in )               [49152 x 256]
  gemm_dr<1><<<dim3(384, 2), 256, 0, stream>>>(
      Y, 1024L, Y, 1024L, 1024,
      Winb, 1024L, 256, 1024, b_in, (const float*)nullptr, X0, (float*)nullptr, 0);

  // 4) LSTM: 3 layers x 6 timesteps; gates = [x_t, h_{t-1}] @ Wl^T + bias (K=512)
  const u16* xin = X0;
  u16* xout = XA;
  for (int l = 0; l < 3; ++l){
    for (int t = 0; t < 6; ++t){
      const u16* a1 = (t == 0) ? zbuf : (xout + (t - 1) * 256);
      long s1 = (t == 0) ? 0L : 1536L;
      gemm_dr<2><<<dim3(64, 8), 256, 0, stream>>>(
          xin + t * 256, 1536L, a1, s1, 256,
          Wl + l * 1024 * 512, 512L, 1024, 512,
          biasL + l * 1024, (const float*)nullptr,
          xout, cbuf, t);
    }
    if (l == 0){ xin = XA; xout = XB; }
    else if (l == 1){ xin = XB; xout = XA; }
  }

  // 5) viewport + score + mean
  k_score<<<2048, 256, 0, stream>>>(XA, Wv, bv, Ws, bs, scoreb);
  k_mean<<<32, 256, 0, stream>>>(scoreb, out);
}

// Round 7
// 739.063 us; speedup vs baseline: 1.2239x; 1.0230x over previous
//
#include <hip/hip_runtime.h>
#include <math.h>
#include <stdint.h>

typedef unsigned short u16;
typedef float f32x4 __attribute__((ext_vector_type(4)));
typedef short bf16x8 __attribute__((ext_vector_type(8)));

#define NVIEW 6

// ---------- helpers ----------
__device__ __forceinline__ u16 f2bf(float f){
  unsigned u = __float_as_uint(f);
  u += 0x7FFFu + ((u >> 16) & 1u);      // round-to-nearest-even
  return (u16)(u >> 16);
}
__device__ __forceinline__ float bf2f(u16 h){
  return __uint_as_float(((unsigned)h) << 16);
}
__device__ __forceinline__ float fsig(float x){
  x = fminf(fmaxf(x, -30.f), 30.f);
  return 1.0f / (1.0f + __expf(-x));
}
__device__ __forceinline__ float ftanh(float x){
  x = fminf(fmaxf(x, -15.f), 15.f);
  float e = __expf(2.0f * x);
  return (e - 1.0f) / (e + 1.0f);
}
// exact GELU via Abramowitz-Stegun 7.1.26 erf (|err| < 1.5e-7, way under bf16 ulp)
__device__ __forceinline__ float gelu_exact(float v){
  float x  = v * 0.70710678118654752f;
  float ax = fabsf(x);
  float t  = 1.0f / fmaf(0.3275911f, ax, 1.0f);
  float p  = t * fmaf(t, fmaf(t, fmaf(t, fmaf(t, 1.061405429f, -1.453152027f),
                                      1.421413741f), -0.284496736f), 0.254829592f);
  float er = copysignf(1.0f - p * __expf(-ax * ax), x);
  return 0.5f * v * (1.0f + er);
}
__device__ __forceinline__ void gload16(const u16* g, u16* l){
  __builtin_amdgcn_global_load_lds((const __attribute__((address_space(1))) unsigned int*)g,
                                   (__attribute__((address_space(3))) unsigned int*)l,
                                   16, 0, 0);
}

// ---------- setup kernels ----------
__global__ void k_cvt(const float* __restrict__ in, u16* __restrict__ out, long n4){
  long i = (long)blockIdx.x * blockDim.x + threadIdx.x;
  long stride = (long)gridDim.x * blockDim.x;
  for (; i < n4; i += stride){
    const float4 v = ((const float4*)in)[i];
    ushort4 o;
    o.x = f2bf(v.x); o.y = f2bf(v.y); o.z = f2bf(v.z); o.w = f2bf(v.w);
    ((ushort4*)out)[i] = o;
  }
}

// Wl[l][4u+q][k] = (k<256 ? Wih[l][q*256+u][k] : Whh[l][q*256+u][k-256]) as bf16
__global__ void k_build_wl(const float* __restrict__ Wih, const float* __restrict__ Whh,
                           u16* __restrict__ Wl){
  int idx = blockIdx.x * 256 + threadIdx.x;   // exactly 3*1024*512 threads
  int l   = idx >> 19;
  int rem = idx & 524287;
  int ro  = rem >> 9;       // interleaved out-row 0..1023
  int k   = rem & 511;
  int u = ro >> 2, q = ro & 3;
  int ri = q * 256 + u;
  float v = (k < 256) ? Wih[(l * 1024 + ri) * 256 + k]
                      : Whh[(l * 1024 + ri) * 256 + (k - 256)];
  Wl[idx] = f2bf(v);
}

__global__ void k_build_bias(const float* __restrict__ bih, const float* __restrict__ bhh,
                             float* __restrict__ biasL, u16* __restrict__ zbuf){
  int idx = blockIdx.x * 256 + threadIdx.x;
  if (idx < 3072){
    int l = idx >> 10; int ro = idx & 1023;
    int u = ro >> 2, q = ro & 3;
    int ri = q * 256 + u;
    biasL[idx] = bih[l * 1024 + ri] + bhh[l * 1024 + ri];
  }
  if (idx < 256) zbuf[idx] = 0;
}

// =====================================================================
// Deep-ring 128x128 GEMM: C[m,n] = sum_k A[m,k]*B[n,k]  (B is [N][K] bf16)
// 256 threads = 4 waves (2M x 2N), wave tile 64x64, BK = 32.
// LDS: 5-slot ring (80 KB) -> 2 blocks/CU; prefetch depth 4; steady-state
// wait vmcnt(12) (waits only loads issued 4 tiles earlier); one drain-free
// s_barrier per tile.
// LDS swizzle (row-pair 8-slot XOR, <=2-way conflict):
//   tile viewed as rp=row>>1 row-pairs of 128 B = 8 slots of 16 B;
//   logical (row,c16) -> s_log=(row&1)*4+c16; physical s_phys=s_log^(rp&7).
//   Staged via inverse permutation on the GLOBAL source + linear LDS dest
//   (rule 21); read addr = rp*128 + s_phys*16, and the XOR term is a
//   per-lane constant since mf steps rp by 8.
// Grid: 1-D, bijective XCD-chunked swizzle, n-fastest decode -> the NBn
// blocks sharing an A-panel run consecutively on ONE XCD (L2 reuse).
// A split in K: cols [0,K0) from A0 (stride sA0), [K0,K) from A1 (sA1).
// EPI 0: out = bf16(gelu_exact(acc+bias[n]) + resid[m*N+n])
// EPI 1: out = bf16(acc+bias[n])
// EPI 2: fused LSTM cell (gate-interleaved N=1024), h->outb, c<->cbuf.
// =====================================================================
template<int EPI>
__global__ __launch_bounds__(256, 2)
void gemm_dr(const u16* __restrict__ A0, long sA0,
             const u16* __restrict__ A1, long sA1, int K0,
             const u16* __restrict__ Bm, long sB,
             int N, int K, int NBn,
             const float* __restrict__ bias,
             const float* __restrict__ resid,
             u16* __restrict__ outb,
             float* __restrict__ cbuf,
             int tstep)
{
  __shared__ __align__(16) u16 lA[5 * 4096];
  __shared__ __align__(16) u16 lB[5 * 4096];

  const int tid  = threadIdx.x;
  const int lane = tid & 63;
  const int wid  = tid >> 6;
  const int wm = wid >> 1, wn = wid & 1;
  const int l15 = lane & 15, lk = lane >> 4;

  // XCD-chunked bijective swizzle (grids are multiples of 8), n fastest
  const int nwg = gridDim.x;
  const int qx  = nwg >> 3;
  const int bb  = blockIdx.x;
  const int swz = (bb & 7) * qx + (bb >> 3);
  const long m0 = (long)(swz / NBn) * 128;
  const int  n0 = (swz % NBn) * 128;
  const int  NT = K >> 5;

  // ---- staging mapping (inverse swizzle on global source) ----
  const int rA0 = tid >> 2;             // 0..63 (row within 64-row half)
  const int cA  = tid & 3;              // physical c16 within row
  const int slog = (((rA0 & 1) << 2) | cA) ^ ((rA0 >> 1) & 7);
  const int srow = (rA0 & ~1) | (slog >> 2);     // source row (0..63) in half
  const int scol = (slog & 3) << 3;              // source col (elements)
  const int ldst = rA0 * 32 + cA * 8;            // linear LDS dest (u16)

  auto STAGE = [&](int slot, int t){
    const int kb = t << 5;
    const int so = slot * 4096;
    #pragma unroll
    for (int c = 0; c < 2; ++c){
      const int r  = c * 64 + srow;
      const int gc = kb + scol;
      const u16* s = (gc < K0) ? (A0 + (m0 + r) * sA0 + gc)
                               : (A1 + (m0 + r) * sA1 + (gc - K0));
      gload16(s, &lA[so + c * 2048 + ldst]);
    }
    #pragma unroll
    for (int c = 0; c < 2; ++c){
      const int r  = c * 64 + srow;
      const int gc = kb + scol;
      gload16(Bm + (long)(n0 + r) * sB + gc, &lB[so + c * 2048 + ldst]);
    }
  };

  f32x4 acc[4][4];
  #pragma unroll
  for (int i = 0; i < 4; ++i)
    #pragma unroll
    for (int j = 0; j < 4; ++j)
      acc[i][j] = (f32x4){0.f, 0.f, 0.f, 0.f};

  // ---- swizzled read offsets (u16 units): rp*64 + s_phys*8 ----
  const int spA = (((l15 & 1) << 2) | lk) ^ (l15 >> 1);   // per-lane constant
  const int rdA = (wm * 32 + (l15 >> 1)) * 64 + spA * 8;
  const int rdB = (wn * 32 + (l15 >> 1)) * 64 + spA * 8;

  auto COMPUTE = [&](int slot){
    const int so = slot * 4096;
    bf16x8 af[4], bq[4];
    #pragma unroll
    for (int mf = 0; mf < 4; ++mf)
      af[mf] = *(const bf16x8*)&lA[so + rdA + mf * 512];
    #pragma unroll
    for (int nf = 0; nf < 4; ++nf)
      bq[nf] = *(const bf16x8*)&lB[so + rdB + nf * 512];
    #pragma unroll
    for (int mf = 0; mf < 4; ++mf)
      #pragma unroll
      for (int nf = 0; nf < 4; ++nf)
        acc[mf][nf] = __builtin_amdgcn_mfma_f32_16x16x32_bf16(af[mf], bq[nf], acc[mf][nf], 0, 0, 0);
  };

  // prologue: fill 4 ring slots
  STAGE(0, 0); STAGE(1, 1); STAGE(2, 2); STAGE(3, 3);

  int sr = 0, sw = 4;
  for (int t = 0; t + 4 <= NT; ++t){          // t = 0 .. NT-4
    asm volatile("s_waitcnt vmcnt(12)" ::: "memory");
    asm volatile("s_barrier" ::: "memory");
    if (t + 4 < NT){ STAGE(sw, t + 4); }
    COMPUTE(sr);
    sr = (sr == 4) ? 0 : sr + 1;
    sw = (sw == 4) ? 0 : sw + 1;
  }
  asm volatile("s_waitcnt vmcnt(8)" ::: "memory");
  asm volatile("s_barrier" ::: "memory");
  COMPUTE(sr); sr = (sr == 4) ? 0 : sr + 1;
  asm volatile("s_waitcnt vmcnt(4)" ::: "memory");
  asm volatile("s_barrier" ::: "memory");
  COMPUTE(sr); sr = (sr == 4) ? 0 : sr + 1;
  asm volatile("s_waitcnt vmcnt(0)" ::: "memory");
  asm volatile("s_barrier" ::: "memory");
  COMPUTE(sr);

  // ---- epilogue ----
  if (EPI == 0 || EPI == 1){
    #pragma unroll
    for (int mf = 0; mf < 4; ++mf){
      #pragma unroll
      for (int nf = 0; nf < 4; ++nf){
        int  n    = n0 + wn * 64 + nf * 16 + l15;
        long mrow = m0 + wm * 64 + mf * 16 + lk * 4;
        float bz = bias[n];
        #pragma unroll
        for (int r = 0; r < 4; ++r){
          float v = acc[mf][nf][r] + bz;
          long off = (mrow + r) * N + n;
          if (EPI == 0) v = gelu_exact(v) + resid[off];
          outb[off] = f2bf(v);
        }
      }
    }
  } else {
    // LSTM cell epilogue. D-frag: row=(lane>>4)*4+reg, col=lane&15.
    // Quad lanes hold gates i,f,g,o of unit u=n>>2; 4x4 quad transpose.
    const int a  = lane & 3;
    const int qb = lane & ~3;
    #pragma unroll
    for (int mf = 0; mf < 4; ++mf){
      #pragma unroll
      for (int nf = 0; nf < 4; ++nf){
        int n = n0 + wn * 64 + nf * 16 + l15;
        float bz = bias[n];
        float v0 = acc[mf][nf][0] + bz;
        float v1 = acc[mf][nf][1] + bz;
        float v2 = acc[mf][nf][2] + bz;
        float v3 = acc[mf][nf][3] + bz;
        float s0 = (a == 0) ? v0 : (a == 1) ? v1 : (a == 2) ? v2 : v3;
        float s1 = (a == 0) ? v1 : (a == 1) ? v2 : (a == 2) ? v3 : v0;
        float s2 = (a == 0) ? v2 : (a == 1) ? v3 : (a == 2) ? v0 : v1;
        float s3 = (a == 0) ? v3 : (a == 1) ? v0 : (a == 2) ? v1 : v2;
        float r0 = s0;
        float r1 = __shfl(s1, qb + ((a + 3) & 3));
        float r2 = __shfl(s2, qb + ((a + 2) & 3));
        float r3 = __shfl(s3, qb + ((a + 1) & 3));
        float wi = (a == 0) ? r0 : (a == 1) ? r1 : (a == 2) ? r2 : r3;
        float wf = (a == 1) ? r0 : (a == 2) ? r1 : (a == 3) ? r2 : r3;
        float wg = (a == 2) ? r0 : (a == 3) ? r1 : (a == 0) ? r2 : r3;
        float wo = (a == 3) ? r0 : (a == 0) ? r1 : (a == 1) ? r2 : r3;
        long row = m0 + wm * 64 + mf * 16 + lk * 4 + a;
        int  u   = ((n0 + wn * 64 + nf * 16) >> 2) + (l15 >> 2);
        float c_old = (tstep == 0) ? 0.0f : cbuf[row * 256 + u];
        float ii = fsig(wi), ff = fsig(wf), gg = ftanh(wg), oo = fsig(wo);
        float cn = ff * c_old + ii * gg;
        float hn = oo * ftanh(cn);
        cbuf[row * 256 + u] = cn;
        outb[(row * NVIEW + tstep) * 256 + u] = f2bf(hn);
      }
    }
  }
}

// ---------- tail: viewport + score + mean ----------
__global__ void k_score(const u16* __restrict__ X3, const float* __restrict__ Wv,
                        const float* __restrict__ bv, const float* __restrict__ Ws,
                        const float* __restrict__ bs, float* __restrict__ score){
  int lane = threadIdx.x & 63;
  int bm = blockIdx.x * 4 + (threadIdx.x >> 6);
  const u16* row = X3 + (long)bm * (NVIEW * 256);
  float4 wv = *(const float4*)(Wv + lane * 4);
  float p = 0.f;
  #pragma unroll
  for (int n = 0; n < NVIEW; ++n){
    ushort4 xv = *(const ushort4*)(row + n * 256 + lane * 4);
    float d = bf2f(xv.x) * wv.x + bf2f(xv.y) * wv.y + bf2f(xv.z) * wv.z + bf2f(xv.w) * wv.w;
    p += Ws[n] * d;
  }
  #pragma unroll
  for (int off = 32; off; off >>= 1) p += __shfl_xor(p, off);
  if (lane == 0){
    float sw = Ws[0] + Ws[1] + Ws[2] + Ws[3] + Ws[4] + Ws[5];
    score[bm] = p + bv[0] * sw + bs[0];
  }
}

__global__ void k_mean(const float* __restrict__ score, float* __restrict__ out){
  __shared__ float red[256];
  int b = blockIdx.x, tid = threadIdx.x;
  red[tid] = score[b * 256 + tid];
  __syncthreads();
  for (int s = 128; s > 0; s >>= 1){
    if (tid < s) red[tid] += red[tid + s];
    __syncthreads();
  }
  if (tid == 0) out[b] = red[0] * (1.0f / 256.0f);
}

// ---------- launcher ----------
extern "C" void kernel_launch(void* const* d_in, const int* in_sizes, int n_in,
                              void* d_out, int out_size, void* d_ws, size_t ws_size,
                              hipStream_t stream){
  const float* swin = (const float*)d_in[0];
  const float* conv = (const float*)d_in[1];
  const float* Wc   = (const float*)d_in[2];
  const float* bc   = (const float*)d_in[3];
  const float* Win  = (const float*)d_in[4];
  const float* b_in = (const float*)d_in[5];
  const float* Wih  = (const float*)d_in[6];
  const float* Whh  = (const float*)d_in[7];
  const float* bih  = (const float*)d_in[8];
  const float* bhh  = (const float*)d_in[9];
  const float* Wv   = (const float*)d_in[10];
  const float* bv   = (const float*)d_in[11];
  const float* Ws   = (const float*)d_in[12];
  const float* bs   = (const float*)d_in[13];
  float* out = (float*)d_out;

  // workspace layout (~207 MB total)
  char* w = (char*)d_ws;
  u16*  convb = (u16*)(w);                    // 100,663,296 B  [49152*1024] bf16
  u16*  X0    = (u16*)(w);                    // reuses convb region after G1
  u16*  XA    = (u16*)(w + 25165824);
  u16*  XB    = (u16*)(w + 50331648);
  float* cbuf = (float*)(w + 75497472);
  u16*  Y     = (u16*)(w + 100663296);        // 100,663,296  (plain [49152][1024])
  u16*  Wcb   = (u16*)(w + 201326592);
  u16*  Winb  = (u16*)(w + 203423744);
  u16*  Wl    = (u16*)(w + 203948032);
  float* biasL= (float*)(w + 207093760);
  u16*  zbuf  = (u16*)(w + 207106048);
  float* scoreb = (float*)(w + 207106560);

  // 1) converts + weight transforms
  k_cvt<<<4096, 256, 0, stream>>>(conv, convb, 49152L * 1024 / 4);
  k_cvt<<<512, 256, 0, stream>>>(Wc, Wcb, 1048576 / 4);
  k_cvt<<<128, 256, 0, stream>>>(Win, Winb, 262144 / 4);
  k_build_wl<<<6144, 256, 0, stream>>>(Wih, Whh, Wl);
  k_build_bias<<<12, 256, 0, stream>>>(bih, bhh, biasL, zbuf);

  // 2) G1: Y = bf16( gelu(conv @ Wc^T + bc) + swin )   [49152 x 1024], NBn=8
  gemm_dr<0><<<3072, 256, 0, stream>>>(
      convb, 1024L, convb, 1024L, 1024,
      Wcb, 1024L, 1024, 1024, 8, bc, swin, Y, (float*)nullptr, 0);

  // 3) G2: X0 = bf16( Y @ Win^T + b_in )               [49152 x 256], NBn=2
  gemm_dr<1><<<768, 256, 0, stream>>>(
      Y, 1024L, Y, 1024L, 1024,
      Winb, 1024L, 256, 1024, 2, b_in, (const float*)nullptr, X0, (float*)nullptr, 0);

  // 4) LSTM: 3 layers x 6 timesteps; gates = [x_t, h_{t-1}] @ Wl^T + bias (K=512)
  const u16* xin = X0;
  u16* xout = XA;
  for (int l = 0; l < 3; ++l){
    for (int t = 0; t < 6; ++t){
      const u16* a1 = (t == 0) ? zbuf : (xout + (t - 1) * 256);
      long s1 = (t == 0) ? 0L : 1536L;
      gemm_dr<2><<<512, 256, 0, stream>>>(
          xin + t * 256, 1536L, a1, s1, 256,
          Wl + l * 1024 * 512, 512L, 1024, 512, 8,
          biasL + l * 1024, (const float*)nullptr,
          xout, cbuf, t);
    }
    if (l == 0){ xin = XA; xout = XB; }
    else if (l == 1){ xin = XB; xout = XA; }
  }

  // 5) viewport + score + mean
  k_score<<<2048, 256, 0, stream>>>(XA, Wv, bv, Ws, bs, scoreb);
  k_mean<<<32, 256, 0, stream>>>(scoreb, out);
}